// Round 5
// baseline (670.467 us; speedup 1.0000x reference)
//
#include <hip/hip_runtime.h>

// ---------------------------------------------------------------------------
// SpGAT: x@W0+b0 -> 8x GAT heads (concat 512) -> GAT(512->64) -> softmax.
// R4: aggregate xp (256 B/edge, all 8 heads at once) then per-head GEMM.
// R6: head scores via MFMA GEMM s16 = xp @ [was||wad]^T.
// R13: CSR via two-level counting sort, zero global atomics.
// R14 (this round): weights decoupled from aggregation.
//   wpass1: streaming pass computes layer-1 edge weights (CSR order) ->
//     w8[E][8] f32 (coalesced) + inv8[N][8]. 1 exp per 8 edges x 8 heads.
//   agg_xp v2: weights/indices read at WAVE-UNIFORM addresses (s_load /
//     broadcast) -- no v_readlane, no exp, no score gather in the hot loop.
//     Per edge: 1 j-load + 1 dword gather + 2 float4 w-loads + 16 fmac.
//   wpass2/agg_final v2: same split for layer 2 (w2[E] + inv2[N]);
//     agg_final drops 27 -> ~6 instrs/edge.
//   Arithmetic identical to R13 (raw f32 weights, inv applied at end).
// ---------------------------------------------------------------------------

using bf16x8 = __bf16 __attribute__((ext_vector_type(8)));
using f32x4  = float  __attribute__((ext_vector_type(4)));

__device__ __forceinline__ unsigned short f2bf(float f) {
    __bf16 h = (__bf16)f;                       // fptrunc, RNE
    return __builtin_bit_cast(unsigned short, h);
}
__device__ __forceinline__ float bflo(unsigned int u) {
    return __builtin_bit_cast(float, u << 16);
}
__device__ __forceinline__ float bfhi(unsigned int u) {
    return __builtin_bit_cast(float, u & 0xffff0000u);
}
__device__ __forceinline__ float bfs(unsigned short u) {
    return __builtin_bit_cast(float, (unsigned)u << 16);
}
__device__ __forceinline__ int rfl(int v) {
    return __builtin_amdgcn_readfirstlane(v);
}
__device__ __forceinline__ float exp2fast(float x) {
#if __has_builtin(__builtin_amdgcn_exp2f)
    return __builtin_amdgcn_exp2f(x);
#else
    return exp2f(x);
#endif
}

#define ALPHA_NEG 0.2f
#define LOG2E 1.44269504088896340736f
#define CHUNK 20000
#define TILE 4096                               // edges per csr block
#define VPT 16                                  // TILE / 256

// --------------------------- merged pack kernel ----------------------------
// blocks 0..63: W0t; 64..319: Ballt; 320..447: Wendt; 448..451: Bscore
__global__ void pack_all(const float* __restrict__ W0, const float* __restrict__ Wh,
                         const float* __restrict__ We, const float* __restrict__ ah,
                         unsigned short* __restrict__ W0t, unsigned short* __restrict__ Ballt,
                         unsigned short* __restrict__ Wendt, unsigned short* __restrict__ Bscore) {
    int b = blockIdx.x, t = threadIdx.x;
    if (b < 64) {                               // W0 [128k][128n] -> [n][k]
        int idx = b * 256 + t;
        int n = idx >> 7, k = idx & 127;
        W0t[n * 128 + k] = f2bf(W0[k * 128 + n]);
    } else if (b < 320) {                       // Wh [8][128k][64f] -> [(h*64+f)][k]
        int idx = (b - 64) * 256 + t;
        int c = idx >> 7, k = idx & 127;
        int h = c >> 6, f = c & 63;
        Ballt[idx] = f2bf(Wh[(h * 128 + k) * 64 + f]);
    } else if (b < 448) {                       // We [512k][64n] -> [n][k]
        int idx = (b - 320) * 256 + t;
        int n = idx >> 9, k = idx & 511;
        Wendt[idx] = f2bf(We[k * 64 + n]);
    } else {                                    // Bscore [16][128], prescaled log2e
        int idx = (b - 448) * 256 + t;
        if (idx < 1024) {
            int h = idx >> 7, k = idx & 127;
            float s = 0.f, d = 0.f;
            for (int f = 0; f < 64; f++) {
                float wv = Wh[(h * 128 + k) * 64 + f];
                s += wv * ah[h * 128 + f];
                d += wv * ah[h * 128 + 64 + f];
            }
            Bscore[h * 128 + k] = f2bf(s * LOG2E);
            Bscore[(8 + h) * 128 + k] = f2bf(d * LOG2E);
        }
    }
}

// ------------------- CSR build: two-level counting sort --------------------
// Coarse bucket = src >> 8 (256 nodes each). hb layout: [blk][512].
__global__ void csr_hist(const int* __restrict__ src, int* __restrict__ hb, int E) {
    __shared__ int h[512];
    int t = threadIdx.x, blk = blockIdx.x;
    h[t] = 0; h[t + 256] = 0;
    __syncthreads();
    int base = blk * TILE + t;
#pragma unroll
    for (int v = 0; v < VPT; v++) {
        int e = base + v * 256;
        if (e < E) atomicAdd(&h[src[e] >> 8], 1);
    }
    __syncthreads();
    hb[blk * 512 + t] = h[t];
    hb[blk * 512 + t + 256] = h[t + 256];
}

// 1 block, 512 threads. Thread t owns bucket t: running prefix over blocks
// (counts -> block-local offsets), then 512-wide scan for bucket bases.
__global__ void csr_scan(int* __restrict__ hb, int* __restrict__ bkt_base, int ablk) {
    __shared__ int s[512];
    int t = threadIdx.x;
    int run = 0;
    for (int b0 = 0; b0 < ablk; b0 += 8) {
        int vv[8];
#pragma unroll
        for (int u = 0; u < 8; u++) {
            int blk = b0 + u;
            vv[u] = (blk < ablk) ? hb[blk * 512 + t] : 0;
        }
#pragma unroll
        for (int u = 0; u < 8; u++) {
            int blk = b0 + u;
            if (blk < ablk) hb[blk * 512 + t] = run;
            run += vv[u];
        }
    }
    s[t] = run;
    __syncthreads();
    for (int off = 1; off < 512; off <<= 1) {
        int add = (t >= off) ? s[t - off] : 0;
        __syncthreads();
        s[t] += add;
        __syncthreads();
    }
    bkt_base[t] = s[t] - run;                   // exclusive base; [nbkt] == E
}

// Atomic-free global scatter: each block's per-bucket range is disjoint.
__global__ void csr_scatter(const int* __restrict__ src, const int* __restrict__ dst,
                            const int* __restrict__ hb, const int* __restrict__ bkt_base,
                            int2* __restrict__ pairs, int E) {
    __shared__ int cur[512];
    int t = threadIdx.x, blk = blockIdx.x;
    cur[t]       = hb[blk * 512 + t]       + bkt_base[t];
    cur[t + 256] = hb[blk * 512 + t + 256] + bkt_base[t + 256];
    __syncthreads();
    int base = blk * TILE + t;
#pragma unroll
    for (int v = 0; v < VPT; v++) {
        int e = base + v * 256;
        if (e < E) {
            int sv = src[e], dv = dst[e];
            int pos = atomicAdd(&cur[sv >> 8], 1);   // LDS atomic
            pairs[pos] = make_int2(sv, dv);
        }
    }
}

// Block per coarse bucket: fine hist over 256 nodes, LDS scan -> row_ptr,
// then place dst into final CSR order.
__global__ void csr_build(const int2* __restrict__ pairs, const int* __restrict__ bkt_base,
                          int* __restrict__ row_ptr, int* __restrict__ dstp, int n) {
    __shared__ int h[256];
    __shared__ int sc[256];
    int t = threadIdx.x, b = blockIdx.x;
    int e0 = bkt_base[b], e1 = bkt_base[b + 1];
    h[t] = 0;
    __syncthreads();
    for (int e = e0 + t; e < e1; e += 256) atomicAdd(&h[pairs[e].x & 255], 1);
    __syncthreads();
    int v = h[t];
    sc[t] = v;
    __syncthreads();
    for (int off = 1; off < 256; off <<= 1) {
        int add = (t >= off) ? sc[t - off] : 0;
        __syncthreads();
        sc[t] += add;
        __syncthreads();
    }
    int excl = sc[t] - v;
    int gid = (b << 8) + t;
    if (gid <= n) row_ptr[gid] = e0 + excl;     // gid==n lands here too (== E)
    h[t] = excl;                                // reuse as cursor
    __syncthreads();
    for (int e = e0 + t; e < e1; e += 256) {
        int2 pr = pairs[e];
        int pos = atomicAdd(&h[pr.x & 255], 1); // LDS atomic
        dstp[e0 + pos] = pr.y;
    }
}

// ------------------------------- MFMA GEMM ---------------------------------
template <int BM, int BN, int K, int WM, int WN, int MT, int NT,
          bool AF32, bool BIAS, bool OBF16, bool ELU, bool BATCHZ>
__launch_bounds__(256)
__global__ void gemm_mfma(const void* __restrict__ Ap, const unsigned short* __restrict__ Bt,
                          const float* __restrict__ bias, void* __restrict__ Cp, int M,
                          int lda, int ldc) {
    constexpr int LDK = 40;                    // pad 32 -> 40 shorts (80B rows, 16B-aligned)
    __shared__ unsigned short As[BM * LDK];
    __shared__ unsigned short Bs[BN * LDK];
    const int t = threadIdx.x;
    const long m0 = (long)blockIdx.x * BM;
    const long n0 = (long)blockIdx.y * BN;
    const int abase = BATCHZ ? blockIdx.z * K : 0;
    const unsigned short* Btz = BATCHZ ? Bt + (size_t)blockIdx.z * BN * K : Bt;
    const long cbase = BATCHZ ? (long)blockIdx.z * BN : 0;
    const int wave = t >> 6, lane = t & 63;
    const int wm = wave / WN, wn = wave % WN;
    const int lrow = lane & 15, lq = lane >> 4;

    f32x4 acc[MT][NT];
#pragma unroll
    for (int a = 0; a < MT; a++)
#pragma unroll
        for (int b = 0; b < NT; b++) acc[a][b] = (f32x4)0.0f;

    for (int kt = 0; kt < K / 32; kt++) {
        const int k0 = kt * 32;
        if constexpr (AF32) {
            const float* A = (const float*)Ap;
#pragma unroll
            for (int it = 0; it < BM * 8 / 256; it++) {
                int L = t + 256 * it;
                int row = L >> 3, kc = (L & 7) * 4;
                long gr = m0 + row;
                float4 v = make_float4(0.f, 0.f, 0.f, 0.f);
                if (gr < M) v = *(const float4*)&A[gr * lda + abase + k0 + kc];
                unsigned int lo = (unsigned)f2bf(v.x) | ((unsigned)f2bf(v.y) << 16);
                unsigned int hi = (unsigned)f2bf(v.z) | ((unsigned)f2bf(v.w) << 16);
                *(uint2*)&As[row * LDK + kc] = make_uint2(lo, hi);
            }
        } else {
            const unsigned short* A = (const unsigned short*)Ap;
#pragma unroll
            for (int it = 0; it < BM * 4 / 256; it++) {
                int L = t + 256 * it;
                int row = L >> 2, kc = (L & 3) * 8;
                long gr = m0 + row;
                uint4 v = make_uint4(0u, 0u, 0u, 0u);
                if (gr < M) v = *(const uint4*)&A[gr * lda + abase + k0 + kc];
                *(uint4*)&As[row * LDK + kc] = v;
            }
        }
#pragma unroll
        for (int it = 0; it < (BN * 4 + 255) / 256; it++) {
            int L = t + 256 * it;
            if (L < BN * 4) {
                int row = L >> 2, kc = (L & 3) * 8;
                *(uint4*)&Bs[row * LDK + kc] = *(const uint4*)&Btz[(n0 + row) * K + k0 + kc];
            }
        }
        __syncthreads();

        bf16x8 af[MT], bfr[NT];
#pragma unroll
        for (int mt = 0; mt < MT; mt++)
            af[mt] = *(const bf16x8*)&As[((wm * MT + mt) * 16 + lrow) * LDK + lq * 8];
#pragma unroll
        for (int nt = 0; nt < NT; nt++)
            bfr[nt] = *(const bf16x8*)&Bs[((wn * NT + nt) * 16 + lrow) * LDK + lq * 8];
#pragma unroll
        for (int mt = 0; mt < MT; mt++)
#pragma unroll
            for (int nt = 0; nt < NT; nt++)
                acc[mt][nt] = __builtin_amdgcn_mfma_f32_16x16x32_bf16(af[mt], bfr[nt],
                                                                     acc[mt][nt], 0, 0, 0);
        __syncthreads();
    }

#pragma unroll
    for (int mt = 0; mt < MT; mt++) {
        long rbase = m0 + (wm * MT + mt) * 16 + lq * 4;
#pragma unroll
        for (int nt = 0; nt < NT; nt++) {
            long col = cbase + n0 + (wn * NT + nt) * 16 + lrow;
            float bv = 0.f;
            if constexpr (BIAS) bv = bias[col];
#pragma unroll
            for (int r = 0; r < 4; r++) {
                long row = rbase + r;
                if (row < M) {
                    float v = acc[mt][nt][r] + bv;
                    if constexpr (ELU) v = v > 0.f ? v : __expf(v) - 1.0f;
                    if constexpr (OBF16)
                        ((unsigned short*)Cp)[row * ldc + col] = f2bf(v);
                    else
                        ((float*)Cp)[row * ldc + col] = v;
                }
            }
        }
    }
}

// --------------------- layer-1 weight pass (R14) ---------------------------
// Wave per node. lane = edge-slot(lane>>3) x head(lane&7). Per 8-edge group:
// 1 dstp load, 1 s16 gather, 1 exp, 1 coalesced 256B store of w8.
// Rowsum falls out per-lane; 3 shfl_xor; lanes 0..7 store inv8.
__global__ void wpass1(const int* __restrict__ row_ptr, const int* __restrict__ dstp,
                       const float* __restrict__ s16, float* __restrict__ w8,
                       float* __restrict__ inv8, int n) {
    int t = threadIdx.x, wave = t >> 6, lane = t & 63;
    int i = blockIdx.x * 4 + wave;
    if (i >= n) return;
    int e0 = rfl(row_ptr[i]);
    int e1 = rfl(row_ptr[i + 1]);
    const int hl = lane & 7, sub8 = lane >> 3;
    float ssv = s16[(size_t)i * 16 + hl];
    float rsl = 0.f;
    for (int p = e0; p < e1; p += 8) {
        int idx = p + sub8;
        int cl = idx < e1 ? idx : e1 - 1;
        int jv = dstp[cl];
        float sc = s16[(size_t)(unsigned)jv * 16 + 8 + hl];
        float s = ssv + sc;
        s = fmaxf(s, ALPHA_NEG * s);            // leaky_relu (scores prescaled log2e)
        float wv = (idx < e1) ? exp2fast(-s) : 0.f;
        rsl += wv;
        if (idx < e1) w8[(size_t)idx * 8 + hl] = wv;
    }
    rsl += __shfl_xor(rsl, 8, 64);
    rsl += __shfl_xor(rsl, 16, 64);
    rsl += __shfl_xor(rsl, 32, 64);
    float inv = 1.0f / (rsl + 1e-16f);
    if (lane < 8) inv8[(size_t)i * 8 + lane] = inv;
}

// ---------------- 8-head xp aggregation v2 (R14) ---------------------------
// Wave per node; lane owns cols {2*lane, 2*lane+1} for all 8 heads.
// Per edge: uniform j (readfirstlane -> SGPR base), 1 dword gather,
// 2 uniform float4 weight loads, 16 fmac. No readlane-broadcast, no exp.
__global__ void agg_xp(const int* __restrict__ row_ptr, const int* __restrict__ dstp,
                       const float* __restrict__ w8, const float* __restrict__ inv8,
                       const unsigned short* __restrict__ xp, unsigned short* __restrict__ z,
                       int n0, int n1) {
    int t = threadIdx.x, wave = t >> 6, lane = t & 63;
    int i = n0 + blockIdx.x * 4 + wave;
    if (i >= n1) return;
    int e0 = rfl(row_ptr[i]);
    int e1 = rfl(row_ptr[i + 1]);
    const int voff = lane << 1;                 // shorts: byte offset lane*4
    float acc[16];
#pragma unroll
    for (int c = 0; c < 16; c++) acc[c] = 0.f;

    for (int p = e0; p < e1; p += 8) {
        int nem = e1 - p;                       // wave-uniform
        unsigned xv[8];
#pragma unroll
        for (int u = 0; u < 8; u++) {
            if (u < nem) {
                int ju = rfl(dstp[p + u]);      // SGPR j -> scalar base addressing
                xv[u] = *(const unsigned*)&xp[(size_t)(unsigned)ju * 128 + voff];
            }
        }
#pragma unroll
        for (int u = 0; u < 8; u++) {
            if (u < nem) {
                const float4 wa = *(const float4*)&w8[(size_t)(p + u) * 8];
                const float4 wb = *(const float4*)&w8[(size_t)(p + u) * 8 + 4];
                float lo = bflo(xv[u]), hi = bfhi(xv[u]);
                acc[0]  += wa.x * lo; acc[1]  += wa.x * hi;
                acc[2]  += wa.y * lo; acc[3]  += wa.y * hi;
                acc[4]  += wa.z * lo; acc[5]  += wa.z * hi;
                acc[6]  += wa.w * lo; acc[7]  += wa.w * hi;
                acc[8]  += wb.x * lo; acc[9]  += wb.x * hi;
                acc[10] += wb.y * lo; acc[11] += wb.y * hi;
                acc[12] += wb.z * lo; acc[13] += wb.z * hi;
                acc[14] += wb.w * lo; acc[15] += wb.w * hi;
            }
        }
    }

    const float4 ia = *(const float4*)&inv8[(size_t)i * 8];
    const float4 ib = *(const float4*)&inv8[(size_t)i * 8 + 4];
    const float iv[8] = {ia.x, ia.y, ia.z, ia.w, ib.x, ib.y, ib.z, ib.w};
    size_t zb = (size_t)(i - n0) * 1024 + voff;
#pragma unroll
    for (int h = 0; h < 8; h++) {
        unsigned pw = (unsigned)f2bf(acc[2 * h] * iv[h]) |
                      ((unsigned)f2bf(acc[2 * h + 1] * iv[h]) << 16);
        *(unsigned*)&z[zb + h * 128] = pw;
    }
}

// ----------------------------- final-layer scores --------------------------
__global__ void scores2(const unsigned short* __restrict__ h2b, const float* __restrict__ ae,
                        float* __restrict__ ss2, float* __restrict__ sd2, int n) {
    int t = threadIdx.x, wave = t >> 6, lane = t & 63;
    int i = blockIdx.x * 4 + wave;
    if (i >= n) return;
    float v = bfs(h2b[(size_t)i * 64 + lane]);
    float a = v * ae[lane];
    float b = v * ae[64 + lane];
    for (int d = 32; d > 0; d >>= 1) {
        a += __shfl_xor(a, d, 64);
        b += __shfl_xor(b, d, 64);
    }
    if (lane == 0) { ss2[i] = a * LOG2E; sd2[i] = b * LOG2E; }  // prescale for exp2
}

// --------------------- layer-2 weight pass (R14) ---------------------------
// Wave per node, lane per edge (chunks of 64): coalesced dstp, sd2 gather,
// 1 exp/edge, coalesced w2 store; butterfly rowsum -> inv2.
__global__ void wpass2(const int* __restrict__ row_ptr, const int* __restrict__ dstp,
                       const float* __restrict__ ss2, const float* __restrict__ sd2,
                       float* __restrict__ w2, float* __restrict__ inv2, int n) {
    int t = threadIdx.x, wave = t >> 6, lane = t & 63;
    int i = blockIdx.x * 4 + wave;
    if (i >= n) return;
    int e0 = rfl(row_ptr[i]);
    int e1 = rfl(row_ptr[i + 1]);
    float ssrc = ss2[i];
    float rsl = 0.f;
    for (int base = e0; base < e1; base += 64) {
        int idx = base + lane;
        int cl = idx < e1 ? idx : e1 - 1;
        int j = dstp[cl];
        float sc = ssrc + sd2[j];
        sc = fmaxf(sc, ALPHA_NEG * sc);         // prescaled log2e
        float wv = (idx < e1) ? exp2fast(-sc) : 0.f;
        rsl += wv;
        if (idx < e1) w2[idx] = wv;
    }
    for (int d = 32; d > 0; d >>= 1) rsl += __shfl_xor(rsl, d, 64);
    if (lane == 0) inv2[i] = 1.0f / (rsl + 1e-16f);
}

// --------------------- final aggregation + row softmax ---------------------
// Wave per node, lane = output col. Per edge: uniform j + uniform w (SGPR),
// 1 ushort gather + 1 unpack + 1 fmac. Softmax epilogue unchanged.
__global__ void agg_final(const int* __restrict__ row_ptr, const int* __restrict__ dstp,
                          const float* __restrict__ w2, const float* __restrict__ inv2,
                          const unsigned short* __restrict__ h2b, float* __restrict__ out,
                          int n) {
    int t = threadIdx.x, wave = t >> 6, lane = t & 63;
    int i = blockIdx.x * 4 + wave;
    if (i >= n) return;
    int e0 = rfl(row_ptr[i]);
    int e1 = rfl(row_ptr[i + 1]);
    float acc = 0.f;
    for (int p = e0; p < e1; p += 8) {
        int nem = e1 - p;                       // wave-uniform
        float vv[8], ww[8];
#pragma unroll
        for (int u = 0; u < 8; u++) {
            if (u < nem) {
                int j = rfl(dstp[p + u]);       // SGPR row base
                vv[u] = bfs(h2b[((size_t)(unsigned)j << 6) + lane]);
                ww[u] = w2[p + u];              // uniform scalar load
            }
        }
#pragma unroll
        for (int u = 0; u < 8; u++)
            if (u < nem) acc += ww[u] * vv[u];
    }
    float o = acc * inv2[i];
    float m = o;
    for (int d = 32; d > 0; d >>= 1) m = fmaxf(m, __shfl_xor(m, d, 64));
    float e = __expf(o - m);
    float s = e;
    for (int d = 32; d > 0; d >>= 1) s += __shfl_xor(s, d, 64);
    out[(size_t)i * 64 + lane] = e / s;
}

// ------------------------------- launcher ----------------------------------
extern "C" void kernel_launch(void* const* d_in, const int* in_sizes, int n_in,
                              void* d_out, int out_size, void* d_ws, size_t ws_size,
                              hipStream_t stream) {
    const float* x  = (const float*)d_in[0];
    const int* edges = (const int*)d_in[1];
    const float* W0 = (const float*)d_in[2];
    const float* b0 = (const float*)d_in[3];
    const float* Wh = (const float*)d_in[4];
    const float* ah = (const float*)d_in[5];
    const float* We = (const float*)d_in[6];
    const float* ae = (const float*)d_in[7];
    float* dout = (float*)d_out;

    const int Nn = in_sizes[0] / 128;   // 100000
    const int E  = in_sizes[1] / 2;     // 1600000
    const int* src = edges;
    const int* dst = edges + E;

    char* p = (char*)d_ws;
    auto alloc = [&](size_t bytes) -> char* {
        char* r = p;
        p += (bytes + 255) & ~(size_t)255;
        return r;
    };
    unsigned short* W0t   = (unsigned short*)alloc(128 * 128 * 2);
    unsigned short* Ballt = (unsigned short*)alloc(512 * 128 * 2);
    unsigned short* Wendt = (unsigned short*)alloc((size_t)64 * 512 * 2);
    unsigned short* Bscore = (unsigned short*)alloc(16 * 128 * 2);
    const int ablk = (E + TILE - 1) / TILE;     // csr edge blocks
    int* hist_blk = (int*)alloc((size_t)ablk * 512 * 4);
    int* bkt_base = (int*)alloc(512 * 4);
    int* row_ptr = (int*)alloc((size_t)(Nn + 1) * 4);
    int* dstp    = (int*)alloc((size_t)E * 4);
    float* s16   = (float*)alloc((size_t)Nn * 16 * 4);
    float* ss2   = (float*)alloc((size_t)Nn * 4);
    float* sd2   = (float*)alloc((size_t)Nn * 4);
    float* w8    = (float*)alloc((size_t)E * 8 * 4);    // layer-1 edge weights
    float* inv8  = (float*)alloc((size_t)Nn * 8 * 4);
    float* inv2  = (float*)alloc((size_t)Nn * 4);
    unsigned short* xp = (unsigned short*)alloc((size_t)Nn * 128 * 2);
    unsigned short* z  = (unsigned short*)alloc((size_t)CHUNK * 1024 * 2); // h2b aliases
    unsigned short* hcat = (unsigned short*)alloc((size_t)Nn * 512 * 2);
    unsigned short* h2b = (unsigned short*)z;   // [N,64] bf16 = 12.8 MB << z
    int2* pairs = (int2*)hcat;          // E int2 = 12.8 MB; hcat dead until chunk loop
    float* w2 = (float*)hcat;           // E f32 = 6.4 MB; hcat dead after Wend GEMM

    size_t needed = (size_t)(p - (char*)d_ws);
    if (needed > ws_size) return;       // diagnostic guard

    const int gm = (Nn + 127) / 128;
    const int nbkt = (Nn + 255) >> 8;   // coarse buckets (256 nodes each)

    pack_all<<<452, 256, 0, stream>>>(W0, Wh, We, ah, W0t, Ballt, Wendt, Bscore);

    // CSR build: no global atomics.
    csr_hist<<<ablk, 256, 0, stream>>>(src, hist_blk, E);
    csr_scan<<<1, 512, 0, stream>>>(hist_blk, bkt_base, ablk);
    csr_scatter<<<ablk, 256, 0, stream>>>(src, dst, hist_blk, bkt_base, pairs, E);
    csr_build<<<nbkt, 256, 0, stream>>>(pairs, bkt_base, row_ptr, dstp, Nn);

    // xp = bf16(x @ W0 + b0)
    gemm_mfma<128, 128, 128, 2, 2, 4, 4, true, true, true, false, false>
        <<<dim3(gm, 1), 256, 0, stream>>>(x, W0t, b0, xp, Nn, 128, 128);

    // s16[N,16] = xp @ Bscore^T  (cols 0..7 = src scores, 8..15 = dst scores)
    gemm_mfma<128, 16, 128, 4, 1, 2, 1, false, false, false, false, false>
        <<<dim3(gm, 1), 256, 0, stream>>>(xp, Bscore, nullptr, s16, Nn, 128, 16);

    // layer-1 edge weights (CSR order) + per-node inverse rowsums
    wpass1<<<(Nn + 3) / 4, 256, 0, stream>>>(row_ptr, dstp, s16, w8, inv8, Nn);

    // chunked: z = normalized xp-aggregation; hcat = ELU(z_h @ W_h) per head
    for (int c0 = 0; c0 < Nn; c0 += CHUNK) {
        int c1 = min(c0 + CHUNK, Nn);
        int Mc = c1 - c0;
        agg_xp<<<(Mc + 3) / 4, 256, 0, stream>>>(row_ptr, dstp, w8, inv8, xp, z, c0, c1);
        gemm_mfma<128, 64, 128, 4, 1, 2, 4, false, false, true, true, true>
            <<<dim3((Mc + 127) / 128, 1, 8), 256, 0, stream>>>(
                z, Ballt, nullptr, hcat + (size_t)c0 * 512, Mc, 1024, 512);
    }

    // h2b = bf16(hcat @ W_end)  [N,64]   (aliases z, now dead)
    gemm_mfma<128, 64, 512, 4, 1, 2, 4, false, false, true, false, false>
        <<<dim3(gm, 1), 256, 0, stream>>>(hcat, Wendt, nullptr, h2b, Nn, 512, 64);

    scores2<<<(Nn + 3) / 4, 256, 0, stream>>>(h2b, ae, ss2, sd2, Nn);
    wpass2<<<(Nn + 3) / 4, 256, 0, stream>>>(row_ptr, dstp, ss2, sd2, w2, inv2, Nn);
    agg_final<<<(Nn + 3) / 4, 256, 0, stream>>>(row_ptr, dstp, w2, inv2, h2b, dout, Nn);
}

// Round 6
// 561.414 us; speedup vs baseline: 1.1942x; 1.1942x over previous
//
#include <hip/hip_runtime.h>

// ---------------------------------------------------------------------------
// SpGAT: x@W0+b0 -> 8x GAT heads (concat 512) -> GAT(512->64) -> softmax.
// R4: aggregate xp (256 B/edge, all 8 heads at once) then per-head GEMM.
// R6: head scores via MFMA GEMM s16 = xp @ [was||wad]^T.
// R10: agg_xp 1 wave/node batched weights; v_readlane broadcasts; exp2.
// R13: CSR via two-level counting sort, zero global atomics.
// R14: REGRESSED (reverted) -- decoupled weight passes added 100MB HBM
//   round-trip and per-edge uniform loads = 2 chained round-trips / 8 edges.
//   Lesson: edge loops are DEPENDENT-LOAD-LATENCY bound, not issue bound.
// R15 (this round): R13 restored; agg_xp windowed-jreg fix:
//   preload 64 edge indices per node into registers (1 coalesced load),
//   per-group j via ds_bpermute (weights) / v_readlane (gathers) -- one
//   dependent hop per 64-edge window instead of 2 per 8-edge group.
// ---------------------------------------------------------------------------

using bf16x8 = __bf16 __attribute__((ext_vector_type(8)));
using f32x4  = float  __attribute__((ext_vector_type(4)));

__device__ __forceinline__ unsigned short f2bf(float f) {
    __bf16 h = (__bf16)f;                       // fptrunc, RNE
    return __builtin_bit_cast(unsigned short, h);
}
__device__ __forceinline__ float bflo(unsigned int u) {
    return __builtin_bit_cast(float, u << 16);
}
__device__ __forceinline__ float bfhi(unsigned int u) {
    return __builtin_bit_cast(float, u & 0xffff0000u);
}
__device__ __forceinline__ float bfs(unsigned short u) {
    return __builtin_bit_cast(float, (unsigned)u << 16);
}
__device__ __forceinline__ int rdlane_i(int v, int l) {
    return __builtin_amdgcn_readlane(v, l);
}
__device__ __forceinline__ float rdlane_f(float v, int l) {
    return __builtin_bit_cast(float, __builtin_amdgcn_readlane(__builtin_bit_cast(int, v), l));
}
__device__ __forceinline__ int rfl(int v) {
    return __builtin_amdgcn_readfirstlane(v);
}
__device__ __forceinline__ float exp2fast(float x) {
#if __has_builtin(__builtin_amdgcn_exp2f)
    return __builtin_amdgcn_exp2f(x);
#else
    return exp2f(x);
#endif
}

#define ALPHA_NEG 0.2f
#define LOG2E 1.44269504088896340736f
#define CHUNK 20000
#define TILE 4096                               // edges per csr block
#define VPT 16                                  // TILE / 256

// --------------------------- merged pack kernel ----------------------------
// blocks 0..63: W0t; 64..319: Ballt; 320..447: Wendt; 448..451: Bscore
__global__ void pack_all(const float* __restrict__ W0, const float* __restrict__ Wh,
                         const float* __restrict__ We, const float* __restrict__ ah,
                         unsigned short* __restrict__ W0t, unsigned short* __restrict__ Ballt,
                         unsigned short* __restrict__ Wendt, unsigned short* __restrict__ Bscore) {
    int b = blockIdx.x, t = threadIdx.x;
    if (b < 64) {                               // W0 [128k][128n] -> [n][k]
        int idx = b * 256 + t;
        int n = idx >> 7, k = idx & 127;
        W0t[n * 128 + k] = f2bf(W0[k * 128 + n]);
    } else if (b < 320) {                       // Wh [8][128k][64f] -> [(h*64+f)][k]
        int idx = (b - 64) * 256 + t;
        int c = idx >> 7, k = idx & 127;
        int h = c >> 6, f = c & 63;
        Ballt[idx] = f2bf(Wh[(h * 128 + k) * 64 + f]);
    } else if (b < 448) {                       // We [512k][64n] -> [n][k]
        int idx = (b - 320) * 256 + t;
        int n = idx >> 9, k = idx & 511;
        Wendt[idx] = f2bf(We[k * 64 + n]);
    } else {                                    // Bscore [16][128], prescaled log2e
        int idx = (b - 448) * 256 + t;
        if (idx < 1024) {
            int h = idx >> 7, k = idx & 127;
            float s = 0.f, d = 0.f;
            for (int f = 0; f < 64; f++) {
                float wv = Wh[(h * 128 + k) * 64 + f];
                s += wv * ah[h * 128 + f];
                d += wv * ah[h * 128 + 64 + f];
            }
            Bscore[h * 128 + k] = f2bf(s * LOG2E);
            Bscore[(8 + h) * 128 + k] = f2bf(d * LOG2E);
        }
    }
}

// ------------------- CSR build: two-level counting sort --------------------
// Coarse bucket = src >> 8 (256 nodes each). hb layout: [blk][512].
__global__ void csr_hist(const int* __restrict__ src, int* __restrict__ hb, int E) {
    __shared__ int h[512];
    int t = threadIdx.x, blk = blockIdx.x;
    h[t] = 0; h[t + 256] = 0;
    __syncthreads();
    int base = blk * TILE + t;
#pragma unroll
    for (int v = 0; v < VPT; v++) {
        int e = base + v * 256;
        if (e < E) atomicAdd(&h[src[e] >> 8], 1);
    }
    __syncthreads();
    hb[blk * 512 + t] = h[t];
    hb[blk * 512 + t + 256] = h[t + 256];
}

// 1 block, 512 threads. Thread t owns bucket t: running prefix over blocks
// (counts -> block-local offsets), then 512-wide scan for bucket bases.
__global__ void csr_scan(int* __restrict__ hb, int* __restrict__ bkt_base, int ablk) {
    __shared__ int s[512];
    int t = threadIdx.x;
    int run = 0;
    for (int b0 = 0; b0 < ablk; b0 += 8) {
        int vv[8];
#pragma unroll
        for (int u = 0; u < 8; u++) {
            int blk = b0 + u;
            vv[u] = (blk < ablk) ? hb[blk * 512 + t] : 0;
        }
#pragma unroll
        for (int u = 0; u < 8; u++) {
            int blk = b0 + u;
            if (blk < ablk) hb[blk * 512 + t] = run;
            run += vv[u];
        }
    }
    s[t] = run;
    __syncthreads();
    for (int off = 1; off < 512; off <<= 1) {
        int add = (t >= off) ? s[t - off] : 0;
        __syncthreads();
        s[t] += add;
        __syncthreads();
    }
    bkt_base[t] = s[t] - run;                   // exclusive base; [nbkt] == E
}

// Atomic-free global scatter: each block's per-bucket range is disjoint.
__global__ void csr_scatter(const int* __restrict__ src, const int* __restrict__ dst,
                            const int* __restrict__ hb, const int* __restrict__ bkt_base,
                            int2* __restrict__ pairs, int E) {
    __shared__ int cur[512];
    int t = threadIdx.x, blk = blockIdx.x;
    cur[t]       = hb[blk * 512 + t]       + bkt_base[t];
    cur[t + 256] = hb[blk * 512 + t + 256] + bkt_base[t + 256];
    __syncthreads();
    int base = blk * TILE + t;
#pragma unroll
    for (int v = 0; v < VPT; v++) {
        int e = base + v * 256;
        if (e < E) {
            int sv = src[e], dv = dst[e];
            int pos = atomicAdd(&cur[sv >> 8], 1);   // LDS atomic
            pairs[pos] = make_int2(sv, dv);
        }
    }
}

// Block per coarse bucket: fine hist over 256 nodes, LDS scan -> row_ptr,
// then place dst into final CSR order.
__global__ void csr_build(const int2* __restrict__ pairs, const int* __restrict__ bkt_base,
                          int* __restrict__ row_ptr, int* __restrict__ dstp, int n) {
    __shared__ int h[256];
    __shared__ int sc[256];
    int t = threadIdx.x, b = blockIdx.x;
    int e0 = bkt_base[b], e1 = bkt_base[b + 1];
    h[t] = 0;
    __syncthreads();
    for (int e = e0 + t; e < e1; e += 256) atomicAdd(&h[pairs[e].x & 255], 1);
    __syncthreads();
    int v = h[t];
    sc[t] = v;
    __syncthreads();
    for (int off = 1; off < 256; off <<= 1) {
        int add = (t >= off) ? sc[t - off] : 0;
        __syncthreads();
        sc[t] += add;
        __syncthreads();
    }
    int excl = sc[t] - v;
    int gid = (b << 8) + t;
    if (gid <= n) row_ptr[gid] = e0 + excl;     // gid==n lands here too (== E)
    h[t] = excl;                                // reuse as cursor
    __syncthreads();
    for (int e = e0 + t; e < e1; e += 256) {
        int2 pr = pairs[e];
        int pos = atomicAdd(&h[pr.x & 255], 1); // LDS atomic
        dstp[e0 + pos] = pr.y;
    }
}

// ------------------------------- MFMA GEMM ---------------------------------
template <int BM, int BN, int K, int WM, int WN, int MT, int NT,
          bool AF32, bool BIAS, bool OBF16, bool ELU, bool BATCHZ>
__launch_bounds__(256)
__global__ void gemm_mfma(const void* __restrict__ Ap, const unsigned short* __restrict__ Bt,
                          const float* __restrict__ bias, void* __restrict__ Cp, int M,
                          int lda, int ldc) {
    constexpr int LDK = 40;                    // pad 32 -> 40 shorts (80B rows, 16B-aligned)
    __shared__ unsigned short As[BM * LDK];
    __shared__ unsigned short Bs[BN * LDK];
    const int t = threadIdx.x;
    const long m0 = (long)blockIdx.x * BM;
    const long n0 = (long)blockIdx.y * BN;
    const int abase = BATCHZ ? blockIdx.z * K : 0;
    const unsigned short* Btz = BATCHZ ? Bt + (size_t)blockIdx.z * BN * K : Bt;
    const long cbase = BATCHZ ? (long)blockIdx.z * BN : 0;
    const int wave = t >> 6, lane = t & 63;
    const int wm = wave / WN, wn = wave % WN;
    const int lrow = lane & 15, lq = lane >> 4;

    f32x4 acc[MT][NT];
#pragma unroll
    for (int a = 0; a < MT; a++)
#pragma unroll
        for (int b = 0; b < NT; b++) acc[a][b] = (f32x4)0.0f;

    for (int kt = 0; kt < K / 32; kt++) {
        const int k0 = kt * 32;
        if constexpr (AF32) {
            const float* A = (const float*)Ap;
#pragma unroll
            for (int it = 0; it < BM * 8 / 256; it++) {
                int L = t + 256 * it;
                int row = L >> 3, kc = (L & 7) * 4;
                long gr = m0 + row;
                float4 v = make_float4(0.f, 0.f, 0.f, 0.f);
                if (gr < M) v = *(const float4*)&A[gr * lda + abase + k0 + kc];
                unsigned int lo = (unsigned)f2bf(v.x) | ((unsigned)f2bf(v.y) << 16);
                unsigned int hi = (unsigned)f2bf(v.z) | ((unsigned)f2bf(v.w) << 16);
                *(uint2*)&As[row * LDK + kc] = make_uint2(lo, hi);
            }
        } else {
            const unsigned short* A = (const unsigned short*)Ap;
#pragma unroll
            for (int it = 0; it < BM * 4 / 256; it++) {
                int L = t + 256 * it;
                int row = L >> 2, kc = (L & 3) * 8;
                long gr = m0 + row;
                uint4 v = make_uint4(0u, 0u, 0u, 0u);
                if (gr < M) v = *(const uint4*)&A[gr * lda + abase + k0 + kc];
                *(uint4*)&As[row * LDK + kc] = v;
            }
        }
#pragma unroll
        for (int it = 0; it < (BN * 4 + 255) / 256; it++) {
            int L = t + 256 * it;
            if (L < BN * 4) {
                int row = L >> 2, kc = (L & 3) * 8;
                *(uint4*)&Bs[row * LDK + kc] = *(const uint4*)&Btz[(n0 + row) * K + k0 + kc];
            }
        }
        __syncthreads();

        bf16x8 af[MT], bfr[NT];
#pragma unroll
        for (int mt = 0; mt < MT; mt++)
            af[mt] = *(const bf16x8*)&As[((wm * MT + mt) * 16 + lrow) * LDK + lq * 8];
#pragma unroll
        for (int nt = 0; nt < NT; nt++)
            bfr[nt] = *(const bf16x8*)&Bs[((wn * NT + nt) * 16 + lrow) * LDK + lq * 8];
#pragma unroll
        for (int mt = 0; mt < MT; mt++)
#pragma unroll
            for (int nt = 0; nt < NT; nt++)
                acc[mt][nt] = __builtin_amdgcn_mfma_f32_16x16x32_bf16(af[mt], bfr[nt],
                                                                     acc[mt][nt], 0, 0, 0);
        __syncthreads();
    }

#pragma unroll
    for (int mt = 0; mt < MT; mt++) {
        long rbase = m0 + (wm * MT + mt) * 16 + lq * 4;
#pragma unroll
        for (int nt = 0; nt < NT; nt++) {
            long col = cbase + n0 + (wn * NT + nt) * 16 + lrow;
            float bv = 0.f;
            if constexpr (BIAS) bv = bias[col];
#pragma unroll
            for (int r = 0; r < 4; r++) {
                long row = rbase + r;
                if (row < M) {
                    float v = acc[mt][nt][r] + bv;
                    if constexpr (ELU) v = v > 0.f ? v : __expf(v) - 1.0f;
                    if constexpr (OBF16)
                        ((unsigned short*)Cp)[row * ldc + col] = f2bf(v);
                    else
                        ((float*)Cp)[row * ldc + col] = v;
                }
            }
        }
    }
}

// ---------------- 8-head xp aggregation v3 (R15) ---------------------------
// Wave per node. Lane owns cols {2*lane, 2*lane+1} for all 8 heads.
// Per 64-edge window: ONE coalesced dstp load into jreg (single dependent
// hop), then per 8-edge group: j for weight-lanes via ds_bpermute(jreg),
// j for gathers via v_readlane(jreg) -- no further load-to-address deps.
// Weights: lane = edge-slot(lane>>3) x head(lane&7), 1 exp per group.
// 16 fmac/edge/lane with readlane weight broadcast (SGPR operand).
__global__ void agg_xp(const int* __restrict__ row_ptr, const int* __restrict__ dstp,
                       const float* __restrict__ s16,
                       const unsigned short* __restrict__ xp, unsigned short* __restrict__ z,
                       int n0, int n1) {
    int t = threadIdx.x, wave = t >> 6, lane = t & 63;
    int i = n0 + blockIdx.x * 4 + wave;
    if (i >= n1) return;
    int e0 = rfl(row_ptr[i]);
    int e1 = rfl(row_ptr[i + 1]);
    const int hl = lane & 7, sub8 = lane >> 3;
    const int voff = lane << 1;                 // shorts: byte offset lane*4
    float ssv = s16[(size_t)i * 16 + hl];
    float acc[16];
#pragma unroll
    for (int c = 0; c < 16; c++) acc[c] = 0.f;
    float rsl = 0.f;

    for (int base = e0; base < e1; base += 64) {
        int m = e1 - base; if (m > 64) m = 64;  // wave-uniform window size
        int jl = lane < m ? lane : m - 1;
        int jreg = dstp[base + jl];             // ONE coalesced load per window

        for (int p = 0; p < m; p += 8) {
            int rel = p + sub8;
            bool ok = rel < m;
            if (!ok) rel = m - 1;
            int jw = __shfl(jreg, rel, 64);     // ds_bpermute, register-only dep
            float sc = s16[(size_t)(unsigned)jw * 16 + 8 + hl];
            float s = ssv + sc;
            s = fmaxf(s, ALPHA_NEG * s);        // leaky_relu (scores prescaled log2e)
            float wv = ok ? exp2fast(-s) : 0.f;
            rsl += wv;
            int nem = m - p;                    // wave-uniform group count
            unsigned xv[8];
#pragma unroll
            for (int u = 0; u < 8; u++) {
                if (u < nem) {
                    int ju = rdlane_i(jreg, p + u);   // SGPR j, register-only dep
                    xv[u] = *(const unsigned*)&xp[(size_t)(unsigned)ju * 128 + voff];
                }
            }
#pragma unroll
            for (int u = 0; u < 8; u++) {
                if (u < nem) {
                    float lo = bflo(xv[u]), hi = bfhi(xv[u]);
#pragma unroll
                    for (int h = 0; h < 8; h++) {
                        float wh = rdlane_f(wv, u * 8 + h);   // SGPR operand for fmac
                        acc[2 * h]     += wh * lo;
                        acc[2 * h + 1] += wh * hi;
                    }
                }
            }
        }
    }

    // rowsum per head: sum lanes with equal (lane&7)
    rsl += __shfl_xor(rsl, 8, 64);
    rsl += __shfl_xor(rsl, 16, 64);
    rsl += __shfl_xor(rsl, 32, 64);
    float inv = 1.0f / (rsl + 1e-16f);
    size_t zb = (size_t)(i - n0) * 1024 + voff;
#pragma unroll
    for (int h = 0; h < 8; h++) {
        float ih = rdlane_f(inv, h);
        unsigned pw = (unsigned)f2bf(acc[2 * h] * ih) |
                      ((unsigned)f2bf(acc[2 * h + 1] * ih) << 16);
        *(unsigned*)&z[zb + h * 128] = pw;
    }
}

// ----------------------------- final-layer scores --------------------------
__global__ void scores2(const unsigned short* __restrict__ h2b, const float* __restrict__ ae,
                        float* __restrict__ ss2, float* __restrict__ sd2, int n) {
    int t = threadIdx.x, wave = t >> 6, lane = t & 63;
    int i = blockIdx.x * 4 + wave;
    if (i >= n) return;
    float v = bfs(h2b[(size_t)i * 64 + lane]);
    float a = v * ae[lane];
    float b = v * ae[64 + lane];
    for (int d = 32; d > 0; d >>= 1) {
        a += __shfl_xor(a, d, 64);
        b += __shfl_xor(b, d, 64);
    }
    if (lane == 0) { ss2[i] = a * LOG2E; sd2[i] = b * LOG2E; }  // prescale for exp2
}

// --------------------- final aggregation + row softmax ---------------------
// Wave per node. Edge chunk of 64: lane L computes weight for edge base+L
// (one exp per edge, ONE coalesced dstp load). Broadcast (w,j) via
// v_readlane (SGPR feeds fmac + scalar row base). 8-deep unroll for MLP.
// Rowsum butterfly deferred to one pass per node. (R13 form)
__global__ void agg_final(const int* __restrict__ row_ptr, const int* __restrict__ dstp,
                          const float* __restrict__ ss2, const float* __restrict__ sd2,
                          const unsigned short* __restrict__ h2b, float* __restrict__ out,
                          int n) {
    int t = threadIdx.x, wave = t >> 6, lane = t & 63;
    int i = blockIdx.x * 4 + wave;
    if (i >= n) return;
    int e0 = rfl(row_ptr[i]);
    int e1 = rfl(row_ptr[i + 1]);
    float ssrc = ss2[i];
    float acc = 0.f, rsl = 0.f;
    for (int base = e0; base < e1; base += 64) {
        int cnt = e1 - base; if (cnt > 64) cnt = 64;
        int jv = 0; float wv = 0.f;
        if (lane < cnt) {
            jv = dstp[base + lane];
            float sc = ssrc + sd2[jv];
            sc = fmaxf(sc, ALPHA_NEG * sc);     // prescaled log2e
            wv = exp2fast(-sc);
        }
        rsl += wv;
        int q = 0;
        for (; q + 8 <= cnt; q += 8) {
            float vv[8], ww[8];
#pragma unroll
            for (int u = 0; u < 8; u++) {
                int j = rdlane_i(jv, q + u);    // SGPR row index
                vv[u] = bfs(h2b[((size_t)(unsigned)j << 6) + lane]);
                ww[u] = rdlane_f(wv, q + u);    // SGPR weight
            }
#pragma unroll
            for (int u = 0; u < 8; u++) acc += ww[u] * vv[u];
        }
        for (; q < cnt; q++) {
            int j = rdlane_i(jv, q);
            float w = rdlane_f(wv, q);
            acc += w * bfs(h2b[((size_t)(unsigned)j << 6) + lane]);
        }
    }
    float rs = rsl;
    for (int d = 32; d > 0; d >>= 1) rs += __shfl_xor(rs, d, 64);
    float o = acc / (rs + 1e-16f);
    float m = o;
    for (int d = 32; d > 0; d >>= 1) m = fmaxf(m, __shfl_xor(m, d, 64));
    float e = __expf(o - m);
    float s = e;
    for (int d = 32; d > 0; d >>= 1) s += __shfl_xor(s, d, 64);
    out[(size_t)i * 64 + lane] = e / s;
}

// ------------------------------- launcher ----------------------------------
extern "C" void kernel_launch(void* const* d_in, const int* in_sizes, int n_in,
                              void* d_out, int out_size, void* d_ws, size_t ws_size,
                              hipStream_t stream) {
    const float* x  = (const float*)d_in[0];
    const int* edges = (const int*)d_in[1];
    const float* W0 = (const float*)d_in[2];
    const float* b0 = (const float*)d_in[3];
    const float* Wh = (const float*)d_in[4];
    const float* ah = (const float*)d_in[5];
    const float* We = (const float*)d_in[6];
    const float* ae = (const float*)d_in[7];
    float* dout = (float*)d_out;

    const int Nn = in_sizes[0] / 128;   // 100000
    const int E  = in_sizes[1] / 2;     // 1600000
    const int* src = edges;
    const int* dst = edges + E;

    char* p = (char*)d_ws;
    auto alloc = [&](size_t bytes) -> char* {
        char* r = p;
        p += (bytes + 255) & ~(size_t)255;
        return r;
    };
    unsigned short* W0t   = (unsigned short*)alloc(128 * 128 * 2);
    unsigned short* Ballt = (unsigned short*)alloc(512 * 128 * 2);
    unsigned short* Wendt = (unsigned short*)alloc((size_t)64 * 512 * 2);
    unsigned short* Bscore = (unsigned short*)alloc(16 * 128 * 2);
    const int ablk = (E + TILE - 1) / TILE;     // csr edge blocks
    int* hist_blk = (int*)alloc((size_t)ablk * 512 * 4);
    int* bkt_base = (int*)alloc(512 * 4);
    int* row_ptr = (int*)alloc((size_t)(Nn + 1) * 4);
    int* dstp    = (int*)alloc((size_t)E * 4);
    float* s16   = (float*)alloc((size_t)Nn * 16 * 4);
    float* ss2   = (float*)alloc((size_t)Nn * 4);
    float* sd2   = (float*)alloc((size_t)Nn * 4);
    unsigned short* xp = (unsigned short*)alloc((size_t)Nn * 128 * 2);
    unsigned short* z  = (unsigned short*)alloc((size_t)CHUNK * 1024 * 2); // h2b aliases
    unsigned short* hcat = (unsigned short*)alloc((size_t)Nn * 512 * 2);
    unsigned short* h2b = (unsigned short*)z;   // [N,64] bf16 = 12.8 MB << z
    int2* pairs = (int2*)hcat;          // E int2 = 12.8 MB; hcat dead until chunk loop

    size_t needed = (size_t)(p - (char*)d_ws);
    if (needed > ws_size) return;       // diagnostic guard

    const int gm = (Nn + 127) / 128;
    const int nbkt = (Nn + 255) >> 8;   // coarse buckets (256 nodes each)

    pack_all<<<452, 256, 0, stream>>>(W0, Wh, We, ah, W0t, Ballt, Wendt, Bscore);

    // CSR build: no global atomics.
    csr_hist<<<ablk, 256, 0, stream>>>(src, hist_blk, E);
    csr_scan<<<1, 512, 0, stream>>>(hist_blk, bkt_base, ablk);
    csr_scatter<<<ablk, 256, 0, stream>>>(src, dst, hist_blk, bkt_base, pairs, E);
    csr_build<<<nbkt, 256, 0, stream>>>(pairs, bkt_base, row_ptr, dstp, Nn);

    // xp = bf16(x @ W0 + b0)
    gemm_mfma<128, 128, 128, 2, 2, 4, 4, true, true, true, false, false>
        <<<dim3(gm, 1), 256, 0, stream>>>(x, W0t, b0, xp, Nn, 128, 128);

    // s16[N,16] = xp @ Bscore^T  (cols 0..7 = src scores, 8..15 = dst scores)
    gemm_mfma<128, 16, 128, 4, 1, 2, 1, false, false, false, false, false>
        <<<dim3(gm, 1), 256, 0, stream>>>(xp, Bscore, nullptr, s16, Nn, 128, 16);

    // chunked: z = normalized xp-aggregation; hcat = ELU(z_h @ W_h) per head
    for (int c0 = 0; c0 < Nn; c0 += CHUNK) {
        int c1 = min(c0 + CHUNK, Nn);
        int Mc = c1 - c0;
        agg_xp<<<(Mc + 3) / 4, 256, 0, stream>>>(row_ptr, dstp, s16, xp, z, c0, c1);
        gemm_mfma<128, 64, 128, 4, 1, 2, 4, false, false, true, true, true>
            <<<dim3((Mc + 127) / 128, 1, 8), 256, 0, stream>>>(
                z, Ballt, nullptr, hcat + (size_t)c0 * 512, Mc, 1024, 512);
    }

    // h2b = bf16(hcat @ W_end)  [N,64]   (aliases z, now dead)
    gemm_mfma<128, 64, 512, 4, 1, 2, 4, false, false, true, false, false>
        <<<dim3(gm, 1), 256, 0, stream>>>(hcat, Wendt, nullptr, h2b, Nn, 512, 64);

    scores2<<<(Nn + 3) / 4, 256, 0, stream>>>(h2b, ae, ss2, sd2, Nn);
    agg_final<<<(Nn + 3) / 4, 256, 0, stream>>>(row_ptr, dstp, ss2, sd2, h2b, dout, Nn);
}

// Round 7
// 526.041 us; speedup vs baseline: 1.2746x; 1.0672x over previous
//
#include <hip/hip_runtime.h>

// ---------------------------------------------------------------------------
// SpGAT: x@W0+b0 -> 8x GAT heads (concat 512) -> GAT(512->64) -> softmax.
// R6: head scores via MFMA GEMM s16 = xp @ [was||wad]^T.
// R13: CSR via two-level counting sort, zero global atomics.
// R14: REGRESSED (reverted) -- lesson: edge loops are dependent-load-latency
//   bound; adding HBM round-trips to cut VALU issue loses.
// R15: windowed-jreg agg_xp (neutral -- TLP already hides gather latency).
// R16 (this round): agg_xp + per-head GEMM FUSED into one kernel.
//   Block = 16 nodes: aggregation writes normalized z rows to LDS
//   (16 x 1032 shorts, 33KB); __syncthreads; MFMA phase (wave = 2 heads,
//   A-frag from LDS, B-frag streamed from L2-resident Ballt) -> ELU ->
//   hcat. Eliminates the z global intermediate entirely (~410MB of
//   write+read traffic across 5 chunks) and 10 dispatch boundaries.
// ---------------------------------------------------------------------------

using bf16x8 = __bf16 __attribute__((ext_vector_type(8)));
using f32x4  = float  __attribute__((ext_vector_type(4)));

__device__ __forceinline__ unsigned short f2bf(float f) {
    __bf16 h = (__bf16)f;                       // fptrunc, RNE
    return __builtin_bit_cast(unsigned short, h);
}
__device__ __forceinline__ float bflo(unsigned int u) {
    return __builtin_bit_cast(float, u << 16);
}
__device__ __forceinline__ float bfhi(unsigned int u) {
    return __builtin_bit_cast(float, u & 0xffff0000u);
}
__device__ __forceinline__ float bfs(unsigned short u) {
    return __builtin_bit_cast(float, (unsigned)u << 16);
}
__device__ __forceinline__ int rdlane_i(int v, int l) {
    return __builtin_amdgcn_readlane(v, l);
}
__device__ __forceinline__ float rdlane_f(float v, int l) {
    return __builtin_bit_cast(float, __builtin_amdgcn_readlane(__builtin_bit_cast(int, v), l));
}
__device__ __forceinline__ int rfl(int v) {
    return __builtin_amdgcn_readfirstlane(v);
}
__device__ __forceinline__ float exp2fast(float x) {
#if __has_builtin(__builtin_amdgcn_exp2f)
    return __builtin_amdgcn_exp2f(x);
#else
    return exp2f(x);
#endif
}

#define ALPHA_NEG 0.2f
#define LOG2E 1.44269504088896340736f
#define TILE 4096                               // edges per csr block
#define VPT 16                                  // TILE / 256
#define NB 16                                   // nodes per fused block
#define LDKZ 1032                               // zs row stride (shorts): 2064B, 16B-aligned

// --------------------------- merged pack kernel ----------------------------
// blocks 0..63: W0t; 64..319: Ballt; 320..447: Wendt; 448..451: Bscore
__global__ void pack_all(const float* __restrict__ W0, const float* __restrict__ Wh,
                         const float* __restrict__ We, const float* __restrict__ ah,
                         unsigned short* __restrict__ W0t, unsigned short* __restrict__ Ballt,
                         unsigned short* __restrict__ Wendt, unsigned short* __restrict__ Bscore) {
    int b = blockIdx.x, t = threadIdx.x;
    if (b < 64) {                               // W0 [128k][128n] -> [n][k]
        int idx = b * 256 + t;
        int n = idx >> 7, k = idx & 127;
        W0t[n * 128 + k] = f2bf(W0[k * 128 + n]);
    } else if (b < 320) {                       // Wh [8][128k][64f] -> [(h*64+f)][k]
        int idx = (b - 64) * 256 + t;
        int c = idx >> 7, k = idx & 127;
        int h = c >> 6, f = c & 63;
        Ballt[idx] = f2bf(Wh[(h * 128 + k) * 64 + f]);
    } else if (b < 448) {                       // We [512k][64n] -> [n][k]
        int idx = (b - 320) * 256 + t;
        int n = idx >> 9, k = idx & 511;
        Wendt[idx] = f2bf(We[k * 64 + n]);
    } else {                                    // Bscore [16][128], prescaled log2e
        int idx = (b - 448) * 256 + t;
        if (idx < 1024) {
            int h = idx >> 7, k = idx & 127;
            float s = 0.f, d = 0.f;
            for (int f = 0; f < 64; f++) {
                float wv = Wh[(h * 128 + k) * 64 + f];
                s += wv * ah[h * 128 + f];
                d += wv * ah[h * 128 + 64 + f];
            }
            Bscore[h * 128 + k] = f2bf(s * LOG2E);
            Bscore[(8 + h) * 128 + k] = f2bf(d * LOG2E);
        }
    }
}

// ------------------- CSR build: two-level counting sort --------------------
// Coarse bucket = src >> 8 (256 nodes each). hb layout: [blk][512].
__global__ void csr_hist(const int* __restrict__ src, int* __restrict__ hb, int E) {
    __shared__ int h[512];
    int t = threadIdx.x, blk = blockIdx.x;
    h[t] = 0; h[t + 256] = 0;
    __syncthreads();
    int base = blk * TILE + t;
#pragma unroll
    for (int v = 0; v < VPT; v++) {
        int e = base + v * 256;
        if (e < E) atomicAdd(&h[src[e] >> 8], 1);
    }
    __syncthreads();
    hb[blk * 512 + t] = h[t];
    hb[blk * 512 + t + 256] = h[t + 256];
}

// 1 block, 512 threads. Thread t owns bucket t: running prefix over blocks
// (counts -> block-local offsets), then 512-wide scan for bucket bases.
__global__ void csr_scan(int* __restrict__ hb, int* __restrict__ bkt_base, int ablk) {
    __shared__ int s[512];
    int t = threadIdx.x;
    int run = 0;
    for (int b0 = 0; b0 < ablk; b0 += 8) {
        int vv[8];
#pragma unroll
        for (int u = 0; u < 8; u++) {
            int blk = b0 + u;
            vv[u] = (blk < ablk) ? hb[blk * 512 + t] : 0;
        }
#pragma unroll
        for (int u = 0; u < 8; u++) {
            int blk = b0 + u;
            if (blk < ablk) hb[blk * 512 + t] = run;
            run += vv[u];
        }
    }
    s[t] = run;
    __syncthreads();
    for (int off = 1; off < 512; off <<= 1) {
        int add = (t >= off) ? s[t - off] : 0;
        __syncthreads();
        s[t] += add;
        __syncthreads();
    }
    bkt_base[t] = s[t] - run;                   // exclusive base; [nbkt] == E
}

// Atomic-free global scatter: each block's per-bucket range is disjoint.
__global__ void csr_scatter(const int* __restrict__ src, const int* __restrict__ dst,
                            const int* __restrict__ hb, const int* __restrict__ bkt_base,
                            int2* __restrict__ pairs, int E) {
    __shared__ int cur[512];
    int t = threadIdx.x, blk = blockIdx.x;
    cur[t]       = hb[blk * 512 + t]       + bkt_base[t];
    cur[t + 256] = hb[blk * 512 + t + 256] + bkt_base[t + 256];
    __syncthreads();
    int base = blk * TILE + t;
#pragma unroll
    for (int v = 0; v < VPT; v++) {
        int e = base + v * 256;
        if (e < E) {
            int sv = src[e], dv = dst[e];
            int pos = atomicAdd(&cur[sv >> 8], 1);   // LDS atomic
            pairs[pos] = make_int2(sv, dv);
        }
    }
}

// Block per coarse bucket: fine hist over 256 nodes, LDS scan -> row_ptr,
// then place dst into final CSR order.
__global__ void csr_build(const int2* __restrict__ pairs, const int* __restrict__ bkt_base,
                          int* __restrict__ row_ptr, int* __restrict__ dstp, int n) {
    __shared__ int h[256];
    __shared__ int sc[256];
    int t = threadIdx.x, b = blockIdx.x;
    int e0 = bkt_base[b], e1 = bkt_base[b + 1];
    h[t] = 0;
    __syncthreads();
    for (int e = e0 + t; e < e1; e += 256) atomicAdd(&h[pairs[e].x & 255], 1);
    __syncthreads();
    int v = h[t];
    sc[t] = v;
    __syncthreads();
    for (int off = 1; off < 256; off <<= 1) {
        int add = (t >= off) ? sc[t - off] : 0;
        __syncthreads();
        sc[t] += add;
        __syncthreads();
    }
    int excl = sc[t] - v;
    int gid = (b << 8) + t;
    if (gid <= n) row_ptr[gid] = e0 + excl;     // gid==n lands here too (== E)
    h[t] = excl;                                // reuse as cursor
    __syncthreads();
    for (int e = e0 + t; e < e1; e += 256) {
        int2 pr = pairs[e];
        int pos = atomicAdd(&h[pr.x & 255], 1); // LDS atomic
        dstp[e0 + pos] = pr.y;
    }
}

// ------------------------------- MFMA GEMM ---------------------------------
template <int BM, int BN, int K, int WM, int WN, int MT, int NT,
          bool AF32, bool BIAS, bool OBF16, bool ELU>
__launch_bounds__(256)
__global__ void gemm_mfma(const void* __restrict__ Ap, const unsigned short* __restrict__ Bt,
                          const float* __restrict__ bias, void* __restrict__ Cp, int M,
                          int lda, int ldc) {
    constexpr int LDK = 40;                    // pad 32 -> 40 shorts (80B rows, 16B-aligned)
    __shared__ unsigned short As[BM * LDK];
    __shared__ unsigned short Bs[BN * LDK];
    const int t = threadIdx.x;
    const long m0 = (long)blockIdx.x * BM;
    const int wave = t >> 6, lane = t & 63;
    const int wm = wave / WN, wn = wave % WN;
    const int lrow = lane & 15, lq = lane >> 4;

    f32x4 acc[MT][NT];
#pragma unroll
    for (int a = 0; a < MT; a++)
#pragma unroll
        for (int b = 0; b < NT; b++) acc[a][b] = (f32x4)0.0f;

    for (int kt = 0; kt < K / 32; kt++) {
        const int k0 = kt * 32;
        if constexpr (AF32) {
            const float* A = (const float*)Ap;
#pragma unroll
            for (int it = 0; it < BM * 8 / 256; it++) {
                int L = t + 256 * it;
                int row = L >> 3, kc = (L & 7) * 4;
                long gr = m0 + row;
                float4 v = make_float4(0.f, 0.f, 0.f, 0.f);
                if (gr < M) v = *(const float4*)&A[gr * lda + k0 + kc];
                unsigned int lo = (unsigned)f2bf(v.x) | ((unsigned)f2bf(v.y) << 16);
                unsigned int hi = (unsigned)f2bf(v.z) | ((unsigned)f2bf(v.w) << 16);
                *(uint2*)&As[row * LDK + kc] = make_uint2(lo, hi);
            }
        } else {
            const unsigned short* A = (const unsigned short*)Ap;
#pragma unroll
            for (int it = 0; it < BM * 4 / 256; it++) {
                int L = t + 256 * it;
                int row = L >> 2, kc = (L & 3) * 8;
                long gr = m0 + row;
                uint4 v = make_uint4(0u, 0u, 0u, 0u);
                if (gr < M) v = *(const uint4*)&A[gr * lda + k0 + kc];
                *(uint4*)&As[row * LDK + kc] = v;
            }
        }
#pragma unroll
        for (int it = 0; it < (BN * 4 + 255) / 256; it++) {
            int L = t + 256 * it;
            if (L < BN * 4) {
                int row = L >> 2, kc = (L & 3) * 8;
                *(uint4*)&Bs[row * LDK + kc] = *(const uint4*)&Bt[(size_t)row * K + k0 + kc];
            }
        }
        __syncthreads();

        bf16x8 af[MT], bfr[NT];
#pragma unroll
        for (int mt = 0; mt < MT; mt++)
            af[mt] = *(const bf16x8*)&As[((wm * MT + mt) * 16 + lrow) * LDK + lq * 8];
#pragma unroll
        for (int nt = 0; nt < NT; nt++)
            bfr[nt] = *(const bf16x8*)&Bs[((wn * NT + nt) * 16 + lrow) * LDK + lq * 8];
#pragma unroll
        for (int mt = 0; mt < MT; mt++)
#pragma unroll
            for (int nt = 0; nt < NT; nt++)
                acc[mt][nt] = __builtin_amdgcn_mfma_f32_16x16x32_bf16(af[mt], bfr[nt],
                                                                     acc[mt][nt], 0, 0, 0);
        __syncthreads();
    }

#pragma unroll
    for (int mt = 0; mt < MT; mt++) {
        long rbase = m0 + (wm * MT + mt) * 16 + lq * 4;
#pragma unroll
        for (int nt = 0; nt < NT; nt++) {
            long col = (wn * NT + nt) * 16 + lrow;
            float bv = 0.f;
            if constexpr (BIAS) bv = bias[col];
#pragma unroll
            for (int r = 0; r < 4; r++) {
                long row = rbase + r;
                if (row < M) {
                    float v = acc[mt][nt][r] + bv;
                    if constexpr (ELU) v = v > 0.f ? v : __expf(v) - 1.0f;
                    if constexpr (OBF16)
                        ((unsigned short*)Cp)[row * ldc + col] = f2bf(v);
                    else
                        ((float*)Cp)[row * ldc + col] = v;
                }
            }
        }
    }
}

// ------------- fused 8-head aggregation + per-head GEMM (R16) --------------
// Block = 16 nodes, 4 waves.
// Phase 1 (agg): wave handles 4 nodes serially; per node, R15's loop: lane
//   owns cols {2*lane,2*lane+1} for all 8 heads; windowed jreg (1 coalesced
//   dstp load / 64 edges); weights 1 exp per 8-edge group; normalized bf16
//   z row written to LDS zs[16][LDKZ] (no global z).
// Phase 2 (MFMA): wave handles 2 heads; A-frag from LDS (proven gemm_mfma
//   mapping, BM=16), B-frag streamed from L2-resident Ballt; ELU -> hcat.
__launch_bounds__(256)
__global__ void agg_gemm(const int* __restrict__ row_ptr, const int* __restrict__ dstp,
                         const float* __restrict__ s16, const unsigned short* __restrict__ xp,
                         const unsigned short* __restrict__ Ballt,
                         unsigned short* __restrict__ hcat, int n) {
    __shared__ unsigned short zs[NB * LDKZ];    // 33KB
    int t = threadIdx.x, wave = t >> 6, lane = t & 63;
    const int hl = lane & 7, sub8 = lane >> 3;
    const int voff = lane << 1;                 // short offset: lane*2 cols
    const int nbase = blockIdx.x * NB;

    // ---------------- phase 1: aggregation into LDS ----------------
    for (int nn = 0; nn < NB / 4; nn++) {
        int ln = wave * (NB / 4) + nn;
        int i = nbase + ln;
        float acc[16];
#pragma unroll
        for (int c = 0; c < 16; c++) acc[c] = 0.f;
        float rsl = 0.f;
        if (i < n) {
            int e0 = rfl(row_ptr[i]);
            int e1 = rfl(row_ptr[i + 1]);
            float ssv = s16[(size_t)i * 16 + hl];
            for (int base = e0; base < e1; base += 64) {
                int mm = e1 - base; if (mm > 64) mm = 64;
                int jl = lane < mm ? lane : mm - 1;
                int jreg = dstp[base + jl];     // ONE coalesced load per window
                for (int p = 0; p < mm; p += 8) {
                    int rel = p + sub8;
                    bool ok = rel < mm;
                    if (!ok) rel = mm - 1;
                    int jw = __shfl(jreg, rel, 64);
                    float sc = s16[(size_t)(unsigned)jw * 16 + 8 + hl];
                    float s = ssv + sc;
                    s = fmaxf(s, ALPHA_NEG * s);
                    float wv = ok ? exp2fast(-s) : 0.f;
                    rsl += wv;
                    int nem = mm - p;
                    unsigned xv[8];
#pragma unroll
                    for (int u = 0; u < 8; u++) {
                        if (u < nem) {
                            int ju = rdlane_i(jreg, p + u);
                            xv[u] = *(const unsigned*)&xp[(size_t)(unsigned)ju * 128 + voff];
                        }
                    }
#pragma unroll
                    for (int u = 0; u < 8; u++) {
                        if (u < nem) {
                            float lo = bflo(xv[u]), hi = bfhi(xv[u]);
#pragma unroll
                            for (int h = 0; h < 8; h++) {
                                float wh = rdlane_f(wv, u * 8 + h);
                                acc[2 * h]     += wh * lo;
                                acc[2 * h + 1] += wh * hi;
                            }
                        }
                    }
                }
            }
        }
        rsl += __shfl_xor(rsl, 8, 64);
        rsl += __shfl_xor(rsl, 16, 64);
        rsl += __shfl_xor(rsl, 32, 64);
        float inv = 1.0f / (rsl + 1e-16f);
#pragma unroll
        for (int h = 0; h < 8; h++) {
            float ih = rdlane_f(inv, h);
            unsigned pw = (unsigned)f2bf(acc[2 * h] * ih) |
                          ((unsigned)f2bf(acc[2 * h + 1] * ih) << 16);
            *(unsigned*)&zs[ln * LDKZ + h * 128 + voff] = pw;
        }
    }
    __syncthreads();

    // ---------------- phase 2: per-head GEMM (MFMA) ----------------
    const int lrow = lane & 15, lq = lane >> 4;
    f32x4 acc2[2][4];
#pragma unroll
    for (int a = 0; a < 2; a++)
#pragma unroll
        for (int b = 0; b < 4; b++) acc2[a][b] = (f32x4)0.0f;

#pragma unroll
    for (int hh = 0; hh < 2; hh++) {
        int h = wave * 2 + hh;
#pragma unroll
        for (int kt = 0; kt < 4; kt++) {
            bf16x8 af = *(const bf16x8*)&zs[lrow * LDKZ + h * 128 + kt * 32 + lq * 8];
#pragma unroll
            for (int nt = 0; nt < 4; nt++) {
                bf16x8 bfr = *(const bf16x8*)&Ballt[(size_t)(h * 64 + nt * 16 + lrow) * 128
                                                    + kt * 32 + lq * 8];
                acc2[hh][nt] = __builtin_amdgcn_mfma_f32_16x16x32_bf16(af, bfr,
                                                                      acc2[hh][nt], 0, 0, 0);
            }
        }
    }

#pragma unroll
    for (int hh = 0; hh < 2; hh++) {
        int h = wave * 2 + hh;
#pragma unroll
        for (int nt = 0; nt < 4; nt++) {
            int col = h * 64 + nt * 16 + lrow;
#pragma unroll
            for (int r = 0; r < 4; r++) {
                int row = nbase + lq * 4 + r;
                if (row < n) {
                    float v = acc2[hh][nt][r];
                    v = v > 0.f ? v : __expf(v) - 1.0f;           // ELU
                    hcat[(size_t)row * 512 + col] = f2bf(v);
                }
            }
        }
    }
}

// ----------------------------- final-layer scores --------------------------
__global__ void scores2(const unsigned short* __restrict__ h2b, const float* __restrict__ ae,
                        float* __restrict__ ss2, float* __restrict__ sd2, int n) {
    int t = threadIdx.x, wave = t >> 6, lane = t & 63;
    int i = blockIdx.x * 4 + wave;
    if (i >= n) return;
    float v = bfs(h2b[(size_t)i * 64 + lane]);
    float a = v * ae[lane];
    float b = v * ae[64 + lane];
    for (int d = 32; d > 0; d >>= 1) {
        a += __shfl_xor(a, d, 64);
        b += __shfl_xor(b, d, 64);
    }
    if (lane == 0) { ss2[i] = a * LOG2E; sd2[i] = b * LOG2E; }  // prescale for exp2
}

// --------------------- final aggregation + row softmax ---------------------
// Wave per node. Edge chunk of 64: lane L computes weight for edge base+L
// (one exp per edge, ONE coalesced dstp load). Broadcast (w,j) via
// v_readlane (SGPR feeds fmac + scalar row base). 8-deep unroll for MLP.
// Rowsum butterfly deferred to one pass per node. (R13 form)
__global__ void agg_final(const int* __restrict__ row_ptr, const int* __restrict__ dstp,
                          const float* __restrict__ ss2, const float* __restrict__ sd2,
                          const unsigned short* __restrict__ h2b, float* __restrict__ out,
                          int n) {
    int t = threadIdx.x, wave = t >> 6, lane = t & 63;
    int i = blockIdx.x * 4 + wave;
    if (i >= n) return;
    int e0 = rfl(row_ptr[i]);
    int e1 = rfl(row_ptr[i + 1]);
    float ssrc = ss2[i];
    float acc = 0.f, rsl = 0.f;
    for (int base = e0; base < e1; base += 64) {
        int cnt = e1 - base; if (cnt > 64) cnt = 64;
        int jv = 0; float wv = 0.f;
        if (lane < cnt) {
            jv = dstp[base + lane];
            float sc = ssrc + sd2[jv];
            sc = fmaxf(sc, ALPHA_NEG * sc);     // prescaled log2e
            wv = exp2fast(-sc);
        }
        rsl += wv;
        int q = 0;
        for (; q + 8 <= cnt; q += 8) {
            float vv[8], ww[8];
#pragma unroll
            for (int u = 0; u < 8; u++) {
                int j = rdlane_i(jv, q + u);    // SGPR row index
                vv[u] = bfs(h2b[((size_t)(unsigned)j << 6) + lane]);
                ww[u] = rdlane_f(wv, q + u);    // SGPR weight
            }
#pragma unroll
            for (int u = 0; u < 8; u++) acc += ww[u] * vv[u];
        }
        for (; q < cnt; q++) {
            int j = rdlane_i(jv, q);
            float w = rdlane_f(wv, q);
            acc += w * bfs(h2b[((size_t)(unsigned)j << 6) + lane]);
        }
    }
    float rs = rsl;
    for (int d = 32; d > 0; d >>= 1) rs += __shfl_xor(rs, d, 64);
    float o = acc / (rs + 1e-16f);
    float m = o;
    for (int d = 32; d > 0; d >>= 1) m = fmaxf(m, __shfl_xor(m, d, 64));
    float e = __expf(o - m);
    float s = e;
    for (int d = 32; d > 0; d >>= 1) s += __shfl_xor(s, d, 64);
    out[(size_t)i * 64 + lane] = e / s;
}

// ------------------------------- launcher ----------------------------------
extern "C" void kernel_launch(void* const* d_in, const int* in_sizes, int n_in,
                              void* d_out, int out_size, void* d_ws, size_t ws_size,
                              hipStream_t stream) {
    const float* x  = (const float*)d_in[0];
    const int* edges = (const int*)d_in[1];
    const float* W0 = (const float*)d_in[2];
    const float* b0 = (const float*)d_in[3];
    const float* Wh = (const float*)d_in[4];
    const float* ah = (const float*)d_in[5];
    const float* We = (const float*)d_in[6];
    const float* ae = (const float*)d_in[7];
    float* dout = (float*)d_out;

    const int Nn = in_sizes[0] / 128;   // 100000
    const int E  = in_sizes[1] / 2;     // 1600000
    const int* src = edges;
    const int* dst = edges + E;

    char* p = (char*)d_ws;
    auto alloc = [&](size_t bytes) -> char* {
        char* r = p;
        p += (bytes + 255) & ~(size_t)255;
        return r;
    };
    unsigned short* W0t   = (unsigned short*)alloc(128 * 128 * 2);
    unsigned short* Ballt = (unsigned short*)alloc(512 * 128 * 2);
    unsigned short* Wendt = (unsigned short*)alloc((size_t)64 * 512 * 2);
    unsigned short* Bscore = (unsigned short*)alloc(16 * 128 * 2);
    const int ablk = (E + TILE - 1) / TILE;     // csr edge blocks
    int* hist_blk = (int*)alloc((size_t)ablk * 512 * 4);
    int* bkt_base = (int*)alloc(512 * 4);
    int* row_ptr = (int*)alloc((size_t)(Nn + 1) * 4);
    int* dstp    = (int*)alloc((size_t)E * 4);
    float* s16   = (float*)alloc((size_t)Nn * 16 * 4);
    float* ss2   = (float*)alloc((size_t)Nn * 4);
    float* sd2   = (float*)alloc((size_t)Nn * 4);
    unsigned short* xp = (unsigned short*)alloc((size_t)Nn * 128 * 2);
    unsigned short* hcat = (unsigned short*)alloc((size_t)Nn * 512 * 2);
    unsigned short* h2b = (unsigned short*)alloc((size_t)Nn * 64 * 2);
    int2* pairs = (int2*)hcat;          // E int2 = 12.8 MB; hcat dead until agg_gemm

    size_t needed = (size_t)(p - (char*)d_ws);
    if (needed > ws_size) return;       // diagnostic guard

    const int gm = (Nn + 127) / 128;
    const int nbkt = (Nn + 255) >> 8;   // coarse buckets (256 nodes each)

    pack_all<<<452, 256, 0, stream>>>(W0, Wh, We, ah, W0t, Ballt, Wendt, Bscore);

    // CSR build: no global atomics.
    csr_hist<<<ablk, 256, 0, stream>>>(src, hist_blk, E);
    csr_scan<<<1, 512, 0, stream>>>(hist_blk, bkt_base, ablk);
    csr_scatter<<<ablk, 256, 0, stream>>>(src, dst, hist_blk, bkt_base, pairs, E);
    csr_build<<<nbkt, 256, 0, stream>>>(pairs, bkt_base, row_ptr, dstp, Nn);

    // xp = bf16(x @ W0 + b0)
    gemm_mfma<128, 128, 128, 2, 2, 4, 4, true, true, true, false>
        <<<dim3(gm, 1), 256, 0, stream>>>(x, W0t, b0, xp, Nn, 128, 128);

    // s16[N,16] = xp @ Bscore^T  (cols 0..7 = src scores, 8..15 = dst scores)
    gemm_mfma<128, 16, 128, 4, 1, 2, 1, false, false, false, false>
        <<<dim3(gm, 1), 256, 0, stream>>>(xp, Bscore, nullptr, s16, Nn, 128, 16);

    // fused: aggregation (LDS z) + per-head GEMM + ELU -> hcat
    agg_gemm<<<(Nn + NB - 1) / NB, 256, 0, stream>>>(row_ptr, dstp, s16, xp,
                                                     Ballt, hcat, Nn);

    // h2b = bf16(hcat @ W_end)  [N,64]
    gemm_mfma<128, 64, 512, 4, 1, 2, 4, false, false, true, false>
        <<<dim3(gm, 1), 256, 0, stream>>>(hcat, Wendt, nullptr, h2b, Nn, 512, 64);

    scores2<<<(Nn + 3) / 4, 256, 0, stream>>>(h2b, ae, ss2, sd2, Nn);
    agg_final<<<(Nn + 3) / 4, 256, 0, stream>>>(row_ptr, dstp, ss2, sd2, h2b, dout, Nn);
}

// Round 8
// 500.025 us; speedup vs baseline: 1.3409x; 1.0520x over previous
//
#include <hip/hip_runtime.h>

// ---------------------------------------------------------------------------
// SpGAT: x@W0+b0 -> 8x GAT heads (concat 512) -> GAT(512->64) -> softmax.
// R6: head scores via MFMA GEMM s16 = xp @ [was||wad]^T.
// R13: CSR via two-level counting sort, zero global atomics.
// R14: REGRESSED (reverted) -- lesson: edge loops are dependent-load-latency
//   bound; adding HBM round-trips to cut VALU issue loses.
// R16: agg_xp + per-head GEMM fused (LDS z, no global intermediate).
// R17 (this round): agg_gemm occupancy 16 -> 32 waves/CU.
//   R16 counters: Occupancy 41%, VALUBusy 52% -- 33KB LDS caps 4 blocks/CU
//   x 4 waves = 16 waves/CU; gather latency unhidden. Fix: 512-thread
//   blocks (8 waves) at SAME NB=16/33KB -> 4 blocks x 8 waves = 32 waves/CU.
//   Phase 1: wave handles 2 nodes; phase 2: wave = 1 head (same mapping).
// ---------------------------------------------------------------------------

using bf16x8 = __bf16 __attribute__((ext_vector_type(8)));
using f32x4  = float  __attribute__((ext_vector_type(4)));

__device__ __forceinline__ unsigned short f2bf(float f) {
    __bf16 h = (__bf16)f;                       // fptrunc, RNE
    return __builtin_bit_cast(unsigned short, h);
}
__device__ __forceinline__ float bflo(unsigned int u) {
    return __builtin_bit_cast(float, u << 16);
}
__device__ __forceinline__ float bfhi(unsigned int u) {
    return __builtin_bit_cast(float, u & 0xffff0000u);
}
__device__ __forceinline__ float bfs(unsigned short u) {
    return __builtin_bit_cast(float, (unsigned)u << 16);
}
__device__ __forceinline__ int rdlane_i(int v, int l) {
    return __builtin_amdgcn_readlane(v, l);
}
__device__ __forceinline__ float rdlane_f(float v, int l) {
    return __builtin_bit_cast(float, __builtin_amdgcn_readlane(__builtin_bit_cast(int, v), l));
}
__device__ __forceinline__ int rfl(int v) {
    return __builtin_amdgcn_readfirstlane(v);
}
__device__ __forceinline__ float exp2fast(float x) {
#if __has_builtin(__builtin_amdgcn_exp2f)
    return __builtin_amdgcn_exp2f(x);
#else
    return exp2f(x);
#endif
}

#define ALPHA_NEG 0.2f
#define LOG2E 1.44269504088896340736f
#define TILE 4096                               // edges per csr block
#define VPT 16                                  // TILE / 256
#define NB 16                                   // nodes per fused block
#define LDKZ 1032                               // zs row stride (shorts): 2064B, 16B-aligned

// --------------------------- merged pack kernel ----------------------------
// blocks 0..63: W0t; 64..319: Ballt; 320..447: Wendt; 448..451: Bscore
__global__ void pack_all(const float* __restrict__ W0, const float* __restrict__ Wh,
                         const float* __restrict__ We, const float* __restrict__ ah,
                         unsigned short* __restrict__ W0t, unsigned short* __restrict__ Ballt,
                         unsigned short* __restrict__ Wendt, unsigned short* __restrict__ Bscore) {
    int b = blockIdx.x, t = threadIdx.x;
    if (b < 64) {                               // W0 [128k][128n] -> [n][k]
        int idx = b * 256 + t;
        int n = idx >> 7, k = idx & 127;
        W0t[n * 128 + k] = f2bf(W0[k * 128 + n]);
    } else if (b < 320) {                       // Wh [8][128k][64f] -> [(h*64+f)][k]
        int idx = (b - 64) * 256 + t;
        int c = idx >> 7, k = idx & 127;
        int h = c >> 6, f = c & 63;
        Ballt[idx] = f2bf(Wh[(h * 128 + k) * 64 + f]);
    } else if (b < 448) {                       // We [512k][64n] -> [n][k]
        int idx = (b - 320) * 256 + t;
        int n = idx >> 9, k = idx & 511;
        Wendt[idx] = f2bf(We[k * 64 + n]);
    } else {                                    // Bscore [16][128], prescaled log2e
        int idx = (b - 448) * 256 + t;
        if (idx < 1024) {
            int h = idx >> 7, k = idx & 127;
            float s = 0.f, d = 0.f;
            for (int f = 0; f < 64; f++) {
                float wv = Wh[(h * 128 + k) * 64 + f];
                s += wv * ah[h * 128 + f];
                d += wv * ah[h * 128 + 64 + f];
            }
            Bscore[h * 128 + k] = f2bf(s * LOG2E);
            Bscore[(8 + h) * 128 + k] = f2bf(d * LOG2E);
        }
    }
}

// ------------------- CSR build: two-level counting sort --------------------
// Coarse bucket = src >> 8 (256 nodes each). hb layout: [blk][512].
__global__ void csr_hist(const int* __restrict__ src, int* __restrict__ hb, int E) {
    __shared__ int h[512];
    int t = threadIdx.x, blk = blockIdx.x;
    h[t] = 0; h[t + 256] = 0;
    __syncthreads();
    int base = blk * TILE + t;
#pragma unroll
    for (int v = 0; v < VPT; v++) {
        int e = base + v * 256;
        if (e < E) atomicAdd(&h[src[e] >> 8], 1);
    }
    __syncthreads();
    hb[blk * 512 + t] = h[t];
    hb[blk * 512 + t + 256] = h[t + 256];
}

// 1 block, 512 threads. Thread t owns bucket t: running prefix over blocks
// (counts -> block-local offsets), then 512-wide scan for bucket bases.
__global__ void csr_scan(int* __restrict__ hb, int* __restrict__ bkt_base, int ablk) {
    __shared__ int s[512];
    int t = threadIdx.x;
    int run = 0;
    for (int b0 = 0; b0 < ablk; b0 += 8) {
        int vv[8];
#pragma unroll
        for (int u = 0; u < 8; u++) {
            int blk = b0 + u;
            vv[u] = (blk < ablk) ? hb[blk * 512 + t] : 0;
        }
#pragma unroll
        for (int u = 0; u < 8; u++) {
            int blk = b0 + u;
            if (blk < ablk) hb[blk * 512 + t] = run;
            run += vv[u];
        }
    }
    s[t] = run;
    __syncthreads();
    for (int off = 1; off < 512; off <<= 1) {
        int add = (t >= off) ? s[t - off] : 0;
        __syncthreads();
        s[t] += add;
        __syncthreads();
    }
    bkt_base[t] = s[t] - run;                   // exclusive base; [nbkt] == E
}

// Atomic-free global scatter: each block's per-bucket range is disjoint.
__global__ void csr_scatter(const int* __restrict__ src, const int* __restrict__ dst,
                            const int* __restrict__ hb, const int* __restrict__ bkt_base,
                            int2* __restrict__ pairs, int E) {
    __shared__ int cur[512];
    int t = threadIdx.x, blk = blockIdx.x;
    cur[t]       = hb[blk * 512 + t]       + bkt_base[t];
    cur[t + 256] = hb[blk * 512 + t + 256] + bkt_base[t + 256];
    __syncthreads();
    int base = blk * TILE + t;
#pragma unroll
    for (int v = 0; v < VPT; v++) {
        int e = base + v * 256;
        if (e < E) {
            int sv = src[e], dv = dst[e];
            int pos = atomicAdd(&cur[sv >> 8], 1);   // LDS atomic
            pairs[pos] = make_int2(sv, dv);
        }
    }
}

// Block per coarse bucket: fine hist over 256 nodes, LDS scan -> row_ptr,
// then place dst into final CSR order.
__global__ void csr_build(const int2* __restrict__ pairs, const int* __restrict__ bkt_base,
                          int* __restrict__ row_ptr, int* __restrict__ dstp, int n) {
    __shared__ int h[256];
    __shared__ int sc[256];
    int t = threadIdx.x, b = blockIdx.x;
    int e0 = bkt_base[b], e1 = bkt_base[b + 1];
    h[t] = 0;
    __syncthreads();
    for (int e = e0 + t; e < e1; e += 256) atomicAdd(&h[pairs[e].x & 255], 1);
    __syncthreads();
    int v = h[t];
    sc[t] = v;
    __syncthreads();
    for (int off = 1; off < 256; off <<= 1) {
        int add = (t >= off) ? sc[t - off] : 0;
        __syncthreads();
        sc[t] += add;
        __syncthreads();
    }
    int excl = sc[t] - v;
    int gid = (b << 8) + t;
    if (gid <= n) row_ptr[gid] = e0 + excl;     // gid==n lands here too (== E)
    h[t] = excl;                                // reuse as cursor
    __syncthreads();
    for (int e = e0 + t; e < e1; e += 256) {
        int2 pr = pairs[e];
        int pos = atomicAdd(&h[pr.x & 255], 1); // LDS atomic
        dstp[e0 + pos] = pr.y;
    }
}

// ------------------------------- MFMA GEMM ---------------------------------
template <int BM, int BN, int K, int WM, int WN, int MT, int NT,
          bool AF32, bool BIAS, bool OBF16, bool ELU>
__launch_bounds__(256)
__global__ void gemm_mfma(const void* __restrict__ Ap, const unsigned short* __restrict__ Bt,
                          const float* __restrict__ bias, void* __restrict__ Cp, int M,
                          int lda, int ldc) {
    constexpr int LDK = 40;                    // pad 32 -> 40 shorts (80B rows, 16B-aligned)
    __shared__ unsigned short As[BM * LDK];
    __shared__ unsigned short Bs[BN * LDK];
    const int t = threadIdx.x;
    const long m0 = (long)blockIdx.x * BM;
    const int wave = t >> 6, lane = t & 63;
    const int wm = wave / WN, wn = wave % WN;
    const int lrow = lane & 15, lq = lane >> 4;

    f32x4 acc[MT][NT];
#pragma unroll
    for (int a = 0; a < MT; a++)
#pragma unroll
        for (int b = 0; b < NT; b++) acc[a][b] = (f32x4)0.0f;

    for (int kt = 0; kt < K / 32; kt++) {
        const int k0 = kt * 32;
        if constexpr (AF32) {
            const float* A = (const float*)Ap;
#pragma unroll
            for (int it = 0; it < BM * 8 / 256; it++) {
                int L = t + 256 * it;
                int row = L >> 3, kc = (L & 7) * 4;
                long gr = m0 + row;
                float4 v = make_float4(0.f, 0.f, 0.f, 0.f);
                if (gr < M) v = *(const float4*)&A[gr * lda + k0 + kc];
                unsigned int lo = (unsigned)f2bf(v.x) | ((unsigned)f2bf(v.y) << 16);
                unsigned int hi = (unsigned)f2bf(v.z) | ((unsigned)f2bf(v.w) << 16);
                *(uint2*)&As[row * LDK + kc] = make_uint2(lo, hi);
            }
        } else {
            const unsigned short* A = (const unsigned short*)Ap;
#pragma unroll
            for (int it = 0; it < BM * 4 / 256; it++) {
                int L = t + 256 * it;
                int row = L >> 2, kc = (L & 3) * 8;
                long gr = m0 + row;
                uint4 v = make_uint4(0u, 0u, 0u, 0u);
                if (gr < M) v = *(const uint4*)&A[gr * lda + k0 + kc];
                *(uint4*)&As[row * LDK + kc] = v;
            }
        }
#pragma unroll
        for (int it = 0; it < (BN * 4 + 255) / 256; it++) {
            int L = t + 256 * it;
            if (L < BN * 4) {
                int row = L >> 2, kc = (L & 3) * 8;
                *(uint4*)&Bs[row * LDK + kc] = *(const uint4*)&Bt[(size_t)row * K + k0 + kc];
            }
        }
        __syncthreads();

        bf16x8 af[MT], bfr[NT];
#pragma unroll
        for (int mt = 0; mt < MT; mt++)
            af[mt] = *(const bf16x8*)&As[((wm * MT + mt) * 16 + lrow) * LDK + lq * 8];
#pragma unroll
        for (int nt = 0; nt < NT; nt++)
            bfr[nt] = *(const bf16x8*)&Bs[((wn * NT + nt) * 16 + lrow) * LDK + lq * 8];
#pragma unroll
        for (int mt = 0; mt < MT; mt++)
#pragma unroll
            for (int nt = 0; nt < NT; nt++)
                acc[mt][nt] = __builtin_amdgcn_mfma_f32_16x16x32_bf16(af[mt], bfr[nt],
                                                                     acc[mt][nt], 0, 0, 0);
        __syncthreads();
    }

#pragma unroll
    for (int mt = 0; mt < MT; mt++) {
        long rbase = m0 + (wm * MT + mt) * 16 + lq * 4;
#pragma unroll
        for (int nt = 0; nt < NT; nt++) {
            long col = (wn * NT + nt) * 16 + lrow;
            float bv = 0.f;
            if constexpr (BIAS) bv = bias[col];
#pragma unroll
            for (int r = 0; r < 4; r++) {
                long row = rbase + r;
                if (row < M) {
                    float v = acc[mt][nt][r] + bv;
                    if constexpr (ELU) v = v > 0.f ? v : __expf(v) - 1.0f;
                    if constexpr (OBF16)
                        ((unsigned short*)Cp)[row * ldc + col] = f2bf(v);
                    else
                        ((float*)Cp)[row * ldc + col] = v;
                }
            }
        }
    }
}

// ------------- fused 8-head aggregation + per-head GEMM (R17) --------------
// Block = 16 nodes, 8 waves (512 thr) -> 4 blocks/CU x 8 = 32 waves/CU.
// Phase 1 (agg): wave handles 2 nodes serially; per node: lane owns cols
//   {2*lane,2*lane+1} for all 8 heads; windowed jreg (1 coalesced dstp load
//   per 64 edges); 1 exp per 8-edge group; normalized bf16 z row -> LDS.
// Phase 2 (MFMA): wave = 1 head; A-frag from LDS zs (proven mapping),
//   B-frag streamed from L2-resident Ballt; ELU -> hcat.
__launch_bounds__(512)
__global__ void agg_gemm(const int* __restrict__ row_ptr, const int* __restrict__ dstp,
                         const float* __restrict__ s16, const unsigned short* __restrict__ xp,
                         const unsigned short* __restrict__ Ballt,
                         unsigned short* __restrict__ hcat, int n) {
    __shared__ unsigned short zs[NB * LDKZ];    // 33KB
    int t = threadIdx.x, wave = t >> 6, lane = t & 63;
    const int hl = lane & 7, sub8 = lane >> 3;
    const int voff = lane << 1;                 // short offset: lane*2 cols
    const int nbase = blockIdx.x * NB;

    // ---------------- phase 1: aggregation into LDS ----------------
    for (int nn = 0; nn < NB / 8; nn++) {
        int ln = wave * (NB / 8) + nn;
        int i = nbase + ln;
        float acc[16];
#pragma unroll
        for (int c = 0; c < 16; c++) acc[c] = 0.f;
        float rsl = 0.f;
        if (i < n) {
            int e0 = rfl(row_ptr[i]);
            int e1 = rfl(row_ptr[i + 1]);
            float ssv = s16[(size_t)i * 16 + hl];
            for (int base = e0; base < e1; base += 64) {
                int mm = e1 - base; if (mm > 64) mm = 64;
                int jl = lane < mm ? lane : mm - 1;
                int jreg = dstp[base + jl];     // ONE coalesced load per window
                for (int p = 0; p < mm; p += 8) {
                    int rel = p + sub8;
                    bool ok = rel < mm;
                    if (!ok) rel = mm - 1;
                    int jw = __shfl(jreg, rel, 64);
                    float sc = s16[(size_t)(unsigned)jw * 16 + 8 + hl];
                    float s = ssv + sc;
                    s = fmaxf(s, ALPHA_NEG * s);
                    float wv = ok ? exp2fast(-s) : 0.f;
                    rsl += wv;
                    int nem = mm - p;
                    unsigned xv[8];
#pragma unroll
                    for (int u = 0; u < 8; u++) {
                        if (u < nem) {
                            int ju = rdlane_i(jreg, p + u);
                            xv[u] = *(const unsigned*)&xp[(size_t)(unsigned)ju * 128 + voff];
                        }
                    }
#pragma unroll
                    for (int u = 0; u < 8; u++) {
                        if (u < nem) {
                            float lo = bflo(xv[u]), hi = bfhi(xv[u]);
#pragma unroll
                            for (int h = 0; h < 8; h++) {
                                float wh = rdlane_f(wv, u * 8 + h);
                                acc[2 * h]     += wh * lo;
                                acc[2 * h + 1] += wh * hi;
                            }
                        }
                    }
                }
            }
        }
        rsl += __shfl_xor(rsl, 8, 64);
        rsl += __shfl_xor(rsl, 16, 64);
        rsl += __shfl_xor(rsl, 32, 64);
        float inv = 1.0f / (rsl + 1e-16f);
#pragma unroll
        for (int h = 0; h < 8; h++) {
            float ih = rdlane_f(inv, h);
            unsigned pw = (unsigned)f2bf(acc[2 * h] * ih) |
                          ((unsigned)f2bf(acc[2 * h + 1] * ih) << 16);
            *(unsigned*)&zs[ln * LDKZ + h * 128 + voff] = pw;
        }
    }
    __syncthreads();

    // ---------------- phase 2: per-head GEMM (MFMA), wave = head ----------
    const int lrow = lane & 15, lq = lane >> 4;
    const int h = wave;
    f32x4 acc2[4];
#pragma unroll
    for (int b = 0; b < 4; b++) acc2[b] = (f32x4)0.0f;

#pragma unroll
    for (int kt = 0; kt < 4; kt++) {
        bf16x8 af = *(const bf16x8*)&zs[lrow * LDKZ + h * 128 + kt * 32 + lq * 8];
#pragma unroll
        for (int nt = 0; nt < 4; nt++) {
            bf16x8 bfr = *(const bf16x8*)&Ballt[(size_t)(h * 64 + nt * 16 + lrow) * 128
                                                + kt * 32 + lq * 8];
            acc2[nt] = __builtin_amdgcn_mfma_f32_16x16x32_bf16(af, bfr, acc2[nt], 0, 0, 0);
        }
    }

#pragma unroll
    for (int nt = 0; nt < 4; nt++) {
        int col = h * 64 + nt * 16 + lrow;
#pragma unroll
        for (int r = 0; r < 4; r++) {
            int row = nbase + lq * 4 + r;
            if (row < n) {
                float v = acc2[nt][r];
                v = v > 0.f ? v : __expf(v) - 1.0f;               // ELU
                hcat[(size_t)row * 512 + col] = f2bf(v);
            }
        }
    }
}

// ----------------------------- final-layer scores --------------------------
__global__ void scores2(const unsigned short* __restrict__ h2b, const float* __restrict__ ae,
                        float* __restrict__ ss2, float* __restrict__ sd2, int n) {
    int t = threadIdx.x, wave = t >> 6, lane = t & 63;
    int i = blockIdx.x * 4 + wave;
    if (i >= n) return;
    float v = bfs(h2b[(size_t)i * 64 + lane]);
    float a = v * ae[lane];
    float b = v * ae[64 + lane];
    for (int d = 32; d > 0; d >>= 1) {
        a += __shfl_xor(a, d, 64);
        b += __shfl_xor(b, d, 64);
    }
    if (lane == 0) { ss2[i] = a * LOG2E; sd2[i] = b * LOG2E; }  // prescale for exp2
}

// --------------------- final aggregation + row softmax ---------------------
// Wave per node. Edge chunk of 64: lane L computes weight for edge base+L
// (one exp per edge, ONE coalesced dstp load). Broadcast (w,j) via
// v_readlane (SGPR feeds fmac + scalar row base). 8-deep unroll for MLP.
// Rowsum butterfly deferred to one pass per node. (R13 form)
__global__ void agg_final(const int* __restrict__ row_ptr, const int* __restrict__ dstp,
                          const float* __restrict__ ss2, const float* __restrict__ sd2,
                          const unsigned short* __restrict__ h2b, float* __restrict__ out,
                          int n) {
    int t = threadIdx.x, wave = t >> 6, lane = t & 63;
    int i = blockIdx.x * 4 + wave;
    if (i >= n) return;
    int e0 = rfl(row_ptr[i]);
    int e1 = rfl(row_ptr[i + 1]);
    float ssrc = ss2[i];
    float acc = 0.f, rsl = 0.f;
    for (int base = e0; base < e1; base += 64) {
        int cnt = e1 - base; if (cnt > 64) cnt = 64;
        int jv = 0; float wv = 0.f;
        if (lane < cnt) {
            jv = dstp[base + lane];
            float sc = ssrc + sd2[jv];
            sc = fmaxf(sc, ALPHA_NEG * sc);     // prescaled log2e
            wv = exp2fast(-sc);
        }
        rsl += wv;
        int q = 0;
        for (; q + 8 <= cnt; q += 8) {
            float vv[8], ww[8];
#pragma unroll
            for (int u = 0; u < 8; u++) {
                int j = rdlane_i(jv, q + u);    // SGPR row index
                vv[u] = bfs(h2b[((size_t)(unsigned)j << 6) + lane]);
                ww[u] = rdlane_f(wv, q + u);    // SGPR weight
            }
#pragma unroll
            for (int u = 0; u < 8; u++) acc += ww[u] * vv[u];
        }
        for (; q < cnt; q++) {
            int j = rdlane_i(jv, q);
            float w = rdlane_f(wv, q);
            acc += w * bfs(h2b[((size_t)(unsigned)j << 6) + lane]);
        }
    }
    float rs = rsl;
    for (int d = 32; d > 0; d >>= 1) rs += __shfl_xor(rs, d, 64);
    float o = acc / (rs + 1e-16f);
    float m = o;
    for (int d = 32; d > 0; d >>= 1) m = fmaxf(m, __shfl_xor(m, d, 64));
    float e = __expf(o - m);
    float s = e;
    for (int d = 32; d > 0; d >>= 1) s += __shfl_xor(s, d, 64);
    out[(size_t)i * 64 + lane] = e / s;
}

// ------------------------------- launcher ----------------------------------
extern "C" void kernel_launch(void* const* d_in, const int* in_sizes, int n_in,
                              void* d_out, int out_size, void* d_ws, size_t ws_size,
                              hipStream_t stream) {
    const float* x  = (const float*)d_in[0];
    const int* edges = (const int*)d_in[1];
    const float* W0 = (const float*)d_in[2];
    const float* b0 = (const float*)d_in[3];
    const float* Wh = (const float*)d_in[4];
    const float* ah = (const float*)d_in[5];
    const float* We = (const float*)d_in[6];
    const float* ae = (const float*)d_in[7];
    float* dout = (float*)d_out;

    const int Nn = in_sizes[0] / 128;   // 100000
    const int E  = in_sizes[1] / 2;     // 1600000
    const int* src = edges;
    const int* dst = edges + E;

    char* p = (char*)d_ws;
    auto alloc = [&](size_t bytes) -> char* {
        char* r = p;
        p += (bytes + 255) & ~(size_t)255;
        return r;
    };
    unsigned short* W0t   = (unsigned short*)alloc(128 * 128 * 2);
    unsigned short* Ballt = (unsigned short*)alloc(512 * 128 * 2);
    unsigned short* Wendt = (unsigned short*)alloc((size_t)64 * 512 * 2);
    unsigned short* Bscore = (unsigned short*)alloc(16 * 128 * 2);
    const int ablk = (E + TILE - 1) / TILE;     // csr edge blocks
    int* hist_blk = (int*)alloc((size_t)ablk * 512 * 4);
    int* bkt_base = (int*)alloc(512 * 4);
    int* row_ptr = (int*)alloc((size_t)(Nn + 1) * 4);
    int* dstp    = (int*)alloc((size_t)E * 4);
    float* s16   = (float*)alloc((size_t)Nn * 16 * 4);
    float* ss2   = (float*)alloc((size_t)Nn * 4);
    float* sd2   = (float*)alloc((size_t)Nn * 4);
    unsigned short* xp = (unsigned short*)alloc((size_t)Nn * 128 * 2);
    unsigned short* hcat = (unsigned short*)alloc((size_t)Nn * 512 * 2);
    unsigned short* h2b = (unsigned short*)alloc((size_t)Nn * 64 * 2);
    int2* pairs = (int2*)hcat;          // E int2 = 12.8 MB; hcat dead until agg_gemm

    size_t needed = (size_t)(p - (char*)d_ws);
    if (needed > ws_size) return;       // diagnostic guard

    const int gm = (Nn + 127) / 128;
    const int nbkt = (Nn + 255) >> 8;   // coarse buckets (256 nodes each)

    pack_all<<<452, 256, 0, stream>>>(W0, Wh, We, ah, W0t, Ballt, Wendt, Bscore);

    // CSR build: no global atomics.
    csr_hist<<<ablk, 256, 0, stream>>>(src, hist_blk, E);
    csr_scan<<<1, 512, 0, stream>>>(hist_blk, bkt_base, ablk);
    csr_scatter<<<ablk, 256, 0, stream>>>(src, dst, hist_blk, bkt_base, pairs, E);
    csr_build<<<nbkt, 256, 0, stream>>>(pairs, bkt_base, row_ptr, dstp, Nn);

    // xp = bf16(x @ W0 + b0)
    gemm_mfma<128, 128, 128, 2, 2, 4, 4, true, true, true, false>
        <<<dim3(gm, 1), 256, 0, stream>>>(x, W0t, b0, xp, Nn, 128, 128);

    // s16[N,16] = xp @ Bscore^T  (cols 0..7 = src scores, 8..15 = dst scores)
    gemm_mfma<128, 16, 128, 4, 1, 2, 1, false, false, false, false>
        <<<dim3(gm, 1), 256, 0, stream>>>(xp, Bscore, nullptr, s16, Nn, 128, 16);

    // fused: aggregation (LDS z) + per-head GEMM + ELU -> hcat
    agg_gemm<<<(Nn + NB - 1) / NB, 512, 0, stream>>>(row_ptr, dstp, s16, xp,
                                                     Ballt, hcat, Nn);

    // h2b = bf16(hcat @ W_end)  [N,64]
    gemm_mfma<128, 64, 512, 4, 1, 2, 4, false, false, true, false>
        <<<dim3(gm, 1), 256, 0, stream>>>(hcat, Wendt, nullptr, h2b, Nn, 512, 64);

    scores2<<<(Nn + 3) / 4, 256, 0, stream>>>(h2b, ae, ss2, sd2, Nn);
    agg_final<<<(Nn + 3) / 4, 256, 0, stream>>>(row_ptr, dstp, ss2, sd2, h2b, dout, Nn);
}

// Round 9
// 497.629 us; speedup vs baseline: 1.3473x; 1.0048x over previous
//
#include <hip/hip_runtime.h>

// ---------------------------------------------------------------------------
// SpGAT: x@W0+b0 -> 8x GAT heads (concat 512) -> GAT(512->64) -> softmax.
// R6: head scores via MFMA GEMM s16 = xp @ [was||wad]^T.
// R13: CSR via two-level counting sort, zero global atomics.
// R14: REGRESSED (reverted) -- lesson: edge loops are dependent-load-latency
//   bound; adding HBM round-trips to cut VALU issue loses.
// R16: agg_xp + per-head GEMM fused (LDS z, no global intermediate).
// R17: 512-thr blocks -> 32 waves/CU (occupancy 41->79%, 200->174us).
// R18 (this round): broadcasts moved VALU -> LDS pipe.
//   agg_gemm phase1: per-group weights stored to per-wave LDS scratch
//   (1 ds_write), read back as wave-uniform ds_read_b64 pairs (broadcast,
//   conflict-free); the pair's two halves feed v_fma operands directly.
//   Removes 8 v_readlane/edge from the VALU pipe (~35% VALU cut).
//   agg_final: same -- ww[u] via LDS broadcast instead of v_readlane.
// ---------------------------------------------------------------------------

using bf16x8 = __bf16 __attribute__((ext_vector_type(8)));
using f32x4  = float  __attribute__((ext_vector_type(4)));
using f32x2  = float  __attribute__((ext_vector_type(2)));

__device__ __forceinline__ unsigned short f2bf(float f) {
    __bf16 h = (__bf16)f;                       // fptrunc, RNE
    return __builtin_bit_cast(unsigned short, h);
}
__device__ __forceinline__ float bflo(unsigned int u) {
    return __builtin_bit_cast(float, u << 16);
}
__device__ __forceinline__ float bfhi(unsigned int u) {
    return __builtin_bit_cast(float, u & 0xffff0000u);
}
__device__ __forceinline__ float bfs(unsigned short u) {
    return __builtin_bit_cast(float, (unsigned)u << 16);
}
__device__ __forceinline__ int rdlane_i(int v, int l) {
    return __builtin_amdgcn_readlane(v, l);
}
__device__ __forceinline__ float rdlane_f(float v, int l) {
    return __builtin_bit_cast(float, __builtin_amdgcn_readlane(__builtin_bit_cast(int, v), l));
}
__device__ __forceinline__ int rfl(int v) {
    return __builtin_amdgcn_readfirstlane(v);
}
__device__ __forceinline__ float exp2fast(float x) {
#if __has_builtin(__builtin_amdgcn_exp2f)
    return __builtin_amdgcn_exp2f(x);
#else
    return exp2f(x);
#endif
}

#define ALPHA_NEG 0.2f
#define LOG2E 1.44269504088896340736f
#define TILE 4096                               // edges per csr block
#define VPT 16                                  // TILE / 256
#define NB 16                                   // nodes per fused block
#define LDKZ 1032                               // zs row stride (shorts): 2064B, 16B-aligned

// --------------------------- merged pack kernel ----------------------------
// blocks 0..63: W0t; 64..319: Ballt; 320..447: Wendt; 448..451: Bscore
__global__ void pack_all(const float* __restrict__ W0, const float* __restrict__ Wh,
                         const float* __restrict__ We, const float* __restrict__ ah,
                         unsigned short* __restrict__ W0t, unsigned short* __restrict__ Ballt,
                         unsigned short* __restrict__ Wendt, unsigned short* __restrict__ Bscore) {
    int b = blockIdx.x, t = threadIdx.x;
    if (b < 64) {                               // W0 [128k][128n] -> [n][k]
        int idx = b * 256 + t;
        int n = idx >> 7, k = idx & 127;
        W0t[n * 128 + k] = f2bf(W0[k * 128 + n]);
    } else if (b < 320) {                       // Wh [8][128k][64f] -> [(h*64+f)][k]
        int idx = (b - 64) * 256 + t;
        int c = idx >> 7, k = idx & 127;
        int h = c >> 6, f = c & 63;
        Ballt[idx] = f2bf(Wh[(h * 128 + k) * 64 + f]);
    } else if (b < 448) {                       // We [512k][64n] -> [n][k]
        int idx = (b - 320) * 256 + t;
        int n = idx >> 9, k = idx & 511;
        Wendt[idx] = f2bf(We[k * 64 + n]);
    } else {                                    // Bscore [16][128], prescaled log2e
        int idx = (b - 448) * 256 + t;
        if (idx < 1024) {
            int h = idx >> 7, k = idx & 127;
            float s = 0.f, d = 0.f;
            for (int f = 0; f < 64; f++) {
                float wv = Wh[(h * 128 + k) * 64 + f];
                s += wv * ah[h * 128 + f];
                d += wv * ah[h * 128 + 64 + f];
            }
            Bscore[h * 128 + k] = f2bf(s * LOG2E);
            Bscore[(8 + h) * 128 + k] = f2bf(d * LOG2E);
        }
    }
}

// ------------------- CSR build: two-level counting sort --------------------
// Coarse bucket = src >> 8 (256 nodes each). hb layout: [blk][512].
__global__ void csr_hist(const int* __restrict__ src, int* __restrict__ hb, int E) {
    __shared__ int h[512];
    int t = threadIdx.x, blk = blockIdx.x;
    h[t] = 0; h[t + 256] = 0;
    __syncthreads();
    int base = blk * TILE + t;
#pragma unroll
    for (int v = 0; v < VPT; v++) {
        int e = base + v * 256;
        if (e < E) atomicAdd(&h[src[e] >> 8], 1);
    }
    __syncthreads();
    hb[blk * 512 + t] = h[t];
    hb[blk * 512 + t + 256] = h[t + 256];
}

// 1 block, 512 threads. Thread t owns bucket t: running prefix over blocks
// (counts -> block-local offsets), then 512-wide scan for bucket bases.
__global__ void csr_scan(int* __restrict__ hb, int* __restrict__ bkt_base, int ablk) {
    __shared__ int s[512];
    int t = threadIdx.x;
    int run = 0;
    for (int b0 = 0; b0 < ablk; b0 += 8) {
        int vv[8];
#pragma unroll
        for (int u = 0; u < 8; u++) {
            int blk = b0 + u;
            vv[u] = (blk < ablk) ? hb[blk * 512 + t] : 0;
        }
#pragma unroll
        for (int u = 0; u < 8; u++) {
            int blk = b0 + u;
            if (blk < ablk) hb[blk * 512 + t] = run;
            run += vv[u];
        }
    }
    s[t] = run;
    __syncthreads();
    for (int off = 1; off < 512; off <<= 1) {
        int add = (t >= off) ? s[t - off] : 0;
        __syncthreads();
        s[t] += add;
        __syncthreads();
    }
    bkt_base[t] = s[t] - run;                   // exclusive base; [nbkt] == E
}

// Atomic-free global scatter: each block's per-bucket range is disjoint.
__global__ void csr_scatter(const int* __restrict__ src, const int* __restrict__ dst,
                            const int* __restrict__ hb, const int* __restrict__ bkt_base,
                            int2* __restrict__ pairs, int E) {
    __shared__ int cur[512];
    int t = threadIdx.x, blk = blockIdx.x;
    cur[t]       = hb[blk * 512 + t]       + bkt_base[t];
    cur[t + 256] = hb[blk * 512 + t + 256] + bkt_base[t + 256];
    __syncthreads();
    int base = blk * TILE + t;
#pragma unroll
    for (int v = 0; v < VPT; v++) {
        int e = base + v * 256;
        if (e < E) {
            int sv = src[e], dv = dst[e];
            int pos = atomicAdd(&cur[sv >> 8], 1);   // LDS atomic
            pairs[pos] = make_int2(sv, dv);
        }
    }
}

// Block per coarse bucket: fine hist over 256 nodes, LDS scan -> row_ptr,
// then place dst into final CSR order.
__global__ void csr_build(const int2* __restrict__ pairs, const int* __restrict__ bkt_base,
                          int* __restrict__ row_ptr, int* __restrict__ dstp, int n) {
    __shared__ int h[256];
    __shared__ int sc[256];
    int t = threadIdx.x, b = blockIdx.x;
    int e0 = bkt_base[b], e1 = bkt_base[b + 1];
    h[t] = 0;
    __syncthreads();
    for (int e = e0 + t; e < e1; e += 256) atomicAdd(&h[pairs[e].x & 255], 1);
    __syncthreads();
    int v = h[t];
    sc[t] = v;
    __syncthreads();
    for (int off = 1; off < 256; off <<= 1) {
        int add = (t >= off) ? sc[t - off] : 0;
        __syncthreads();
        sc[t] += add;
        __syncthreads();
    }
    int excl = sc[t] - v;
    int gid = (b << 8) + t;
    if (gid <= n) row_ptr[gid] = e0 + excl;     // gid==n lands here too (== E)
    h[t] = excl;                                // reuse as cursor
    __syncthreads();
    for (int e = e0 + t; e < e1; e += 256) {
        int2 pr = pairs[e];
        int pos = atomicAdd(&h[pr.x & 255], 1); // LDS atomic
        dstp[e0 + pos] = pr.y;
    }
}

// ------------------------------- MFMA GEMM ---------------------------------
template <int BM, int BN, int K, int WM, int WN, int MT, int NT,
          bool AF32, bool BIAS, bool OBF16, bool ELU>
__launch_bounds__(256)
__global__ void gemm_mfma(const void* __restrict__ Ap, const unsigned short* __restrict__ Bt,
                          const float* __restrict__ bias, void* __restrict__ Cp, int M,
                          int lda, int ldc) {
    constexpr int LDK = 40;                    // pad 32 -> 40 shorts (80B rows, 16B-aligned)
    __shared__ unsigned short As[BM * LDK];
    __shared__ unsigned short Bs[BN * LDK];
    const int t = threadIdx.x;
    const long m0 = (long)blockIdx.x * BM;
    const int wave = t >> 6, lane = t & 63;
    const int wm = wave / WN, wn = wave % WN;
    const int lrow = lane & 15, lq = lane >> 4;

    f32x4 acc[MT][NT];
#pragma unroll
    for (int a = 0; a < MT; a++)
#pragma unroll
        for (int b = 0; b < NT; b++) acc[a][b] = (f32x4)0.0f;

    for (int kt = 0; kt < K / 32; kt++) {
        const int k0 = kt * 32;
        if constexpr (AF32) {
            const float* A = (const float*)Ap;
#pragma unroll
            for (int it = 0; it < BM * 8 / 256; it++) {
                int L = t + 256 * it;
                int row = L >> 3, kc = (L & 7) * 4;
                long gr = m0 + row;
                float4 v = make_float4(0.f, 0.f, 0.f, 0.f);
                if (gr < M) v = *(const float4*)&A[gr * lda + k0 + kc];
                unsigned int lo = (unsigned)f2bf(v.x) | ((unsigned)f2bf(v.y) << 16);
                unsigned int hi = (unsigned)f2bf(v.z) | ((unsigned)f2bf(v.w) << 16);
                *(uint2*)&As[row * LDK + kc] = make_uint2(lo, hi);
            }
        } else {
            const unsigned short* A = (const unsigned short*)Ap;
#pragma unroll
            for (int it = 0; it < BM * 4 / 256; it++) {
                int L = t + 256 * it;
                int row = L >> 2, kc = (L & 3) * 8;
                long gr = m0 + row;
                uint4 v = make_uint4(0u, 0u, 0u, 0u);
                if (gr < M) v = *(const uint4*)&A[gr * lda + k0 + kc];
                *(uint4*)&As[row * LDK + kc] = v;
            }
        }
#pragma unroll
        for (int it = 0; it < (BN * 4 + 255) / 256; it++) {
            int L = t + 256 * it;
            if (L < BN * 4) {
                int row = L >> 2, kc = (L & 3) * 8;
                *(uint4*)&Bs[row * LDK + kc] = *(const uint4*)&Bt[(size_t)row * K + k0 + kc];
            }
        }
        __syncthreads();

        bf16x8 af[MT], bfr[NT];
#pragma unroll
        for (int mt = 0; mt < MT; mt++)
            af[mt] = *(const bf16x8*)&As[((wm * MT + mt) * 16 + lrow) * LDK + lq * 8];
#pragma unroll
        for (int nt = 0; nt < NT; nt++)
            bfr[nt] = *(const bf16x8*)&Bs[((wn * NT + nt) * 16 + lrow) * LDK + lq * 8];
#pragma unroll
        for (int mt = 0; mt < MT; mt++)
#pragma unroll
            for (int nt = 0; nt < NT; nt++)
                acc[mt][nt] = __builtin_amdgcn_mfma_f32_16x16x32_bf16(af[mt], bfr[nt],
                                                                     acc[mt][nt], 0, 0, 0);
        __syncthreads();
    }

#pragma unroll
    for (int mt = 0; mt < MT; mt++) {
        long rbase = m0 + (wm * MT + mt) * 16 + lq * 4;
#pragma unroll
        for (int nt = 0; nt < NT; nt++) {
            long col = (wn * NT + nt) * 16 + lrow;
            float bv = 0.f;
            if constexpr (BIAS) bv = bias[col];
#pragma unroll
            for (int r = 0; r < 4; r++) {
                long row = rbase + r;
                if (row < M) {
                    float v = acc[mt][nt][r] + bv;
                    if constexpr (ELU) v = v > 0.f ? v : __expf(v) - 1.0f;
                    if constexpr (OBF16)
                        ((unsigned short*)Cp)[row * ldc + col] = f2bf(v);
                    else
                        ((float*)Cp)[row * ldc + col] = v;
                }
            }
        }
    }
}

// ------------- fused 8-head aggregation + per-head GEMM (R18) --------------
// Block = 16 nodes, 8 waves (512 thr) -> 4 blocks/CU x 8 = 32 waves/CU.
// Phase 1 (agg): wave handles 2 nodes serially; lane owns cols
//   {2*lane,2*lane+1} for all 8 heads; windowed jreg (1 coalesced dstp load
//   per 64 edges); 1 exp per 8-edge group. Weights go through per-wave LDS
//   scratch: 1 ds_write, then wave-uniform ds_read_b64 pairs (broadcast,
//   conflict-free) feed v_fma operands -- no v_readlane on the VALU pipe.
// Phase 2 (MFMA): wave = 1 head; A-frag from LDS zs, B-frag from L2-resident
//   Ballt; ELU -> hcat.
__launch_bounds__(512, 8)
__global__ void agg_gemm(const int* __restrict__ row_ptr, const int* __restrict__ dstp,
                         const float* __restrict__ s16, const unsigned short* __restrict__ xp,
                         const unsigned short* __restrict__ Ballt,
                         unsigned short* __restrict__ hcat, int n) {
    __shared__ unsigned short zs[NB * LDKZ];    // 33KB
    __shared__ float wlds[8][64];               // per-wave weight scratch (2KB)
    int t = threadIdx.x, wave = t >> 6, lane = t & 63;
    const int hl = lane & 7, sub8 = lane >> 3;
    const int voff = lane << 1;                 // short offset: lane*2 cols
    const int nbase = blockIdx.x * NB;

    // ---------------- phase 1: aggregation into LDS ----------------
    for (int nn = 0; nn < NB / 8; nn++) {
        int ln = wave * (NB / 8) + nn;
        int i = nbase + ln;
        float acc[16];
#pragma unroll
        for (int c = 0; c < 16; c++) acc[c] = 0.f;
        float rsl = 0.f;
        if (i < n) {
            int e0 = rfl(row_ptr[i]);
            int e1 = rfl(row_ptr[i + 1]);
            float ssv = s16[(size_t)i * 16 + hl];
            for (int base = e0; base < e1; base += 64) {
                int mm = e1 - base; if (mm > 64) mm = 64;
                int jl = lane < mm ? lane : mm - 1;
                int jreg = dstp[base + jl];     // ONE coalesced load per window
                for (int p = 0; p < mm; p += 8) {
                    int rel = p + sub8;
                    bool ok = rel < mm;
                    if (!ok) rel = mm - 1;
                    int jw = __shfl(jreg, rel, 64);
                    float sc = s16[(size_t)(unsigned)jw * 16 + 8 + hl];
                    float s = ssv + sc;
                    s = fmaxf(s, ALPHA_NEG * s);
                    float wv = ok ? exp2fast(-s) : 0.f;
                    rsl += wv;
                    __builtin_amdgcn_wave_barrier();
                    wlds[wave][lane] = wv;      // lane = edge*8 + head
                    __builtin_amdgcn_wave_barrier();
                    int nem = mm - p;
                    unsigned xv[8];
#pragma unroll
                    for (int u = 0; u < 8; u++) {
                        if (u < nem) {
                            int ju = rdlane_i(jreg, p + u);
                            xv[u] = *(const unsigned*)&xp[(size_t)(unsigned)ju * 128 + voff];
                        }
                    }
#pragma unroll
                    for (int u = 0; u < 8; u++) {
                        if (u < nem) {
                            float lo = bflo(xv[u]), hi = bfhi(xv[u]);
                            const f32x2* wrow = (const f32x2*)&wlds[wave][u * 8];
#pragma unroll
                            for (int p2 = 0; p2 < 4; p2++) {
                                f32x2 wp = wrow[p2];    // ds_read_b64 broadcast
                                acc[4 * p2]     += wp[0] * lo;
                                acc[4 * p2 + 1] += wp[0] * hi;
                                acc[4 * p2 + 2] += wp[1] * lo;
                                acc[4 * p2 + 3] += wp[1] * hi;
                            }
                        }
                    }
                }
            }
        }
        rsl += __shfl_xor(rsl, 8, 64);
        rsl += __shfl_xor(rsl, 16, 64);
        rsl += __shfl_xor(rsl, 32, 64);
        float inv = 1.0f / (rsl + 1e-16f);
#pragma unroll
        for (int h = 0; h < 8; h++) {
            float ih = rdlane_f(inv, h);
            unsigned pw = (unsigned)f2bf(acc[2 * h] * ih) |
                          ((unsigned)f2bf(acc[2 * h + 1] * ih) << 16);
            *(unsigned*)&zs[ln * LDKZ + h * 128 + voff] = pw;
        }
    }
    __syncthreads();

    // ---------------- phase 2: per-head GEMM (MFMA), wave = head ----------
    const int lrow = lane & 15, lq = lane >> 4;
    const int h = wave;
    f32x4 acc2[4];
#pragma unroll
    for (int b = 0; b < 4; b++) acc2[b] = (f32x4)0.0f;

#pragma unroll
    for (int kt = 0; kt < 4; kt++) {
        bf16x8 af = *(const bf16x8*)&zs[lrow * LDKZ + h * 128 + kt * 32 + lq * 8];
#pragma unroll
        for (int nt = 0; nt < 4; nt++) {
            bf16x8 bfr = *(const bf16x8*)&Ballt[(size_t)(h * 64 + nt * 16 + lrow) * 128
                                                + kt * 32 + lq * 8];
            acc2[nt] = __builtin_amdgcn_mfma_f32_16x16x32_bf16(af, bfr, acc2[nt], 0, 0, 0);
        }
    }

#pragma unroll
    for (int nt = 0; nt < 4; nt++) {
        int col = h * 64 + nt * 16 + lrow;
#pragma unroll
        for (int r = 0; r < 4; r++) {
            int row = nbase + lq * 4 + r;
            if (row < n) {
                float v = acc2[nt][r];
                v = v > 0.f ? v : __expf(v) - 1.0f;               // ELU
                hcat[(size_t)row * 512 + col] = f2bf(v);
            }
        }
    }
}

// ----------------------------- final-layer scores --------------------------
__global__ void scores2(const unsigned short* __restrict__ h2b, const float* __restrict__ ae,
                        float* __restrict__ ss2, float* __restrict__ sd2, int n) {
    int t = threadIdx.x, wave = t >> 6, lane = t & 63;
    int i = blockIdx.x * 4 + wave;
    if (i >= n) return;
    float v = bfs(h2b[(size_t)i * 64 + lane]);
    float a = v * ae[lane];
    float b = v * ae[64 + lane];
    for (int d = 32; d > 0; d >>= 1) {
        a += __shfl_xor(a, d, 64);
        b += __shfl_xor(b, d, 64);
    }
    if (lane == 0) { ss2[i] = a * LOG2E; sd2[i] = b * LOG2E; }  // prescale for exp2
}

// --------------------- final aggregation + row softmax ---------------------
// Wave per node. Edge chunk of 64: lane L computes weight for edge base+L
// (one exp per edge, ONE coalesced dstp load). j broadcast via v_readlane
// (SGPR row base); w broadcast via per-wave LDS scratch (ds_read, off the
// VALU pipe). 8-deep unroll for MLP. Rowsum deferred to node end.
__global__ void agg_final(const int* __restrict__ row_ptr, const int* __restrict__ dstp,
                          const float* __restrict__ ss2, const float* __restrict__ sd2,
                          const unsigned short* __restrict__ h2b, float* __restrict__ out,
                          int n) {
    __shared__ float wlds2[4][64];
    int t = threadIdx.x, wave = t >> 6, lane = t & 63;
    int i = blockIdx.x * 4 + wave;
    if (i >= n) return;
    int e0 = rfl(row_ptr[i]);
    int e1 = rfl(row_ptr[i + 1]);
    float ssrc = ss2[i];
    float acc = 0.f, rsl = 0.f;
    for (int base = e0; base < e1; base += 64) {
        int cnt = e1 - base; if (cnt > 64) cnt = 64;
        int jv = 0; float wv = 0.f;
        if (lane < cnt) {
            jv = dstp[base + lane];
            float sc = ssrc + sd2[jv];
            sc = fmaxf(sc, ALPHA_NEG * sc);     // prescaled log2e
            wv = exp2fast(-sc);
        }
        rsl += wv;
        __builtin_amdgcn_wave_barrier();
        wlds2[wave][lane] = wv;
        __builtin_amdgcn_wave_barrier();
        int q = 0;
        for (; q + 8 <= cnt; q += 8) {
            float vv[8], ww[8];
#pragma unroll
            for (int u = 0; u < 8; u++) {
                int j = rdlane_i(jv, q + u);    // SGPR row index
                vv[u] = bfs(h2b[((size_t)(unsigned)j << 6) + lane]);
            }
#pragma unroll
            for (int u = 0; u < 8; u++) ww[u] = wlds2[wave][q + u];  // LDS broadcast
#pragma unroll
            for (int u = 0; u < 8; u++) acc += ww[u] * vv[u];
        }
        for (; q < cnt; q++) {
            int j = rdlane_i(jv, q);
            float w = wlds2[wave][q];
            acc += w * bfs(h2b[((size_t)(unsigned)j << 6) + lane]);
        }
    }
    float rs = rsl;
    for (int d = 32; d > 0; d >>= 1) rs += __shfl_xor(rs, d, 64);
    float o = acc / (rs + 1e-16f);
    float m = o;
    for (int d = 32; d > 0; d >>= 1) m = fmaxf(m, __shfl_xor(m, d, 64));
    float e = __expf(o - m);
    float s = e;
    for (int d = 32; d > 0; d >>= 1) s += __shfl_xor(s, d, 64);
    out[(size_t)i * 64 + lane] = e / s;
}

// ------------------------------- launcher ----------------------------------
extern "C" void kernel_launch(void* const* d_in, const int* in_sizes, int n_in,
                              void* d_out, int out_size, void* d_ws, size_t ws_size,
                              hipStream_t stream) {
    const float* x  = (const float*)d_in[0];
    const int* edges = (const int*)d_in[1];
    const float* W0 = (const float*)d_in[2];
    const float* b0 = (const float*)d_in[3];
    const float* Wh = (const float*)d_in[4];
    const float* ah = (const float*)d_in[5];
    const float* We = (const float*)d_in[6];
    const float* ae = (const float*)d_in[7];
    float* dout = (float*)d_out;

    const int Nn = in_sizes[0] / 128;   // 100000
    const int E  = in_sizes[1] / 2;     // 1600000
    const int* src = edges;
    const int* dst = edges + E;

    char* p = (char*)d_ws;
    auto alloc = [&](size_t bytes) -> char* {
        char* r = p;
        p += (bytes + 255) & ~(size_t)255;
        return r;
    };
    unsigned short* W0t   = (unsigned short*)alloc(128 * 128 * 2);
    unsigned short* Ballt = (unsigned short*)alloc(512 * 128 * 2);
    unsigned short* Wendt = (unsigned short*)alloc((size_t)64 * 512 * 2);
    unsigned short* Bscore = (unsigned short*)alloc(16 * 128 * 2);
    const int ablk = (E + TILE - 1) / TILE;     // csr edge blocks
    int* hist_blk = (int*)alloc((size_t)ablk * 512 * 4);
    int* bkt_base = (int*)alloc(512 * 4);
    int* row_ptr = (int*)alloc((size_t)(Nn + 1) * 4);
    int* dstp    = (int*)alloc((size_t)E * 4);
    float* s16   = (float*)alloc((size_t)Nn * 16 * 4);
    float* ss2   = (float*)alloc((size_t)Nn * 4);
    float* sd2   = (float*)alloc((size_t)Nn * 4);
    unsigned short* xp = (unsigned short*)alloc((size_t)Nn * 128 * 2);
    unsigned short* hcat = (unsigned short*)alloc((size_t)Nn * 512 * 2);
    unsigned short* h2b = (unsigned short*)alloc((size_t)Nn * 64 * 2);
    int2* pairs = (int2*)hcat;          // E int2 = 12.8 MB; hcat dead until agg_gemm

    size_t needed = (size_t)(p - (char*)d_ws);
    if (needed > ws_size) return;       // diagnostic guard

    const int gm = (Nn + 127) / 128;
    const int nbkt = (Nn + 255) >> 8;   // coarse buckets (256 nodes each)

    pack_all<<<452, 256, 0, stream>>>(W0, Wh, We, ah, W0t, Ballt, Wendt, Bscore);

    // CSR build: no global atomics.
    csr_hist<<<ablk, 256, 0, stream>>>(src, hist_blk, E);
    csr_scan<<<1, 512, 0, stream>>>(hist_blk, bkt_base, ablk);
    csr_scatter<<<ablk, 256, 0, stream>>>(src, dst, hist_blk, bkt_base, pairs, E);
    csr_build<<<nbkt, 256, 0, stream>>>(pairs, bkt_base, row_ptr, dstp, Nn);

    // xp = bf16(x @ W0 + b0)
    gemm_mfma<128, 128, 128, 2, 2, 4, 4, true, true, true, false>
        <<<dim3(gm, 1), 256, 0, stream>>>(x, W0t, b0, xp, Nn, 128, 128);

    // s16[N,16] = xp @ Bscore^T  (cols 0..7 = src scores, 8..15 = dst scores)
    gemm_mfma<128, 16, 128, 4, 1, 2, 1, false, false, false, false>
        <<<dim3(gm, 1), 256, 0, stream>>>(xp, Bscore, nullptr, s16, Nn, 128, 16);

    // fused: aggregation (LDS z) + per-head GEMM + ELU -> hcat
    agg_gemm<<<(Nn + NB - 1) / NB, 512, 0, stream>>>(row_ptr, dstp, s16, xp,
                                                     Ballt, hcat, Nn);

    // h2b = bf16(hcat @ W_end)  [N,64]
    gemm_mfma<128, 64, 512, 4, 1, 2, 4, false, false, true, false>
        <<<dim3(gm, 1), 256, 0, stream>>>(hcat, Wendt, nullptr, h2b, Nn, 512, 64);

    scores2<<<(Nn + 3) / 4, 256, 0, stream>>>(h2b, ae, ss2, sd2, Nn);
    agg_final<<<(Nn + 3) / 4, 256, 0, stream>>>(row_ptr, dstp, ss2, sd2, h2b, dout, Nn);
}